// Round 6
// baseline (754.225 us; speedup 1.0000x reference)
//
#include <hip/hip_runtime.h>
#include <hip/hip_bf16.h>

#define NN 100000
#define EE 1600000
#define GG 64
#define HH 128
#define LL 3
#define BN_EPS 1e-5f
#define NBUCK 196          // ceil(NN/512)
#define BCAP 12288         // bucket capacity (mean 8163, +45 sigma safe)
#define PART_CHUNK 8192
#define NREP 16            // stats replicas

typedef __attribute__((ext_vector_type(8))) short bf16x8;
typedef __attribute__((ext_vector_type(4))) float f32x4;
typedef unsigned int uint32;

__device__ __forceinline__ unsigned short f2bf(float f) {
    uint32 x = __float_as_uint(f);
    uint32 r = (x + 0x7fffu + ((x >> 16) & 1u)) >> 16;
    return (unsigned short)r;
}
__device__ __forceinline__ float bf2f(unsigned short u) { return __uint_as_float(((uint32)u) << 16); }
// dequant-accumulate 4 unsigned uint8 channels with per-row scale
__device__ __forceinline__ void accq(float4& a, uint32 u, float sc) {
    a.x += sc * (float)(u & 0xffu);
    a.y += sc * (float)((u >> 8) & 0xffu);
    a.z += sc * (float)((u >> 16) & 0xffu);
    a.w += sc * (float)(u >> 24);
}
__device__ __forceinline__ uint32 ld32(const unsigned char* p, uint32 off) {
    return *(const uint32*)(p + off);
}
__device__ __forceinline__ float ldf(const float* p, uint32 byteoff) {
    return *(const float*)((const char*)p + byteoff);
}

// ---------------- bucketed edge partition ----------------
__global__ __launch_bounds__(256) void partition_kernel(
    const int* __restrict__ src, const int* __restrict__ dst,
    int* __restrict__ bcnt, uint32* __restrict__ part) {
    __shared__ int cnt[NBUCK];
    __shared__ int loff[NBUCK + 1];
    __shared__ int gpos[NBUCK];
    __shared__ int lcur[NBUCK];
    __shared__ uint32 buf[PART_CHUNK];
    int tid = threadIdx.x;
    int base = blockIdx.x * PART_CHUNK;
    int n = min(PART_CHUNK, EE - base);
    for (int i = tid; i < NBUCK; i += 256) { cnt[i] = 0; lcur[i] = 0; }
    __syncthreads();
    for (int i = tid; i < n; i += 256) atomicAdd(&cnt[dst[base + i] >> 9], 1);
    __syncthreads();
    if (tid == 0) {
        int acc = 0;
        for (int b = 0; b < NBUCK; ++b) { loff[b] = acc; acc += cnt[b]; }
        loff[NBUCK] = acc;
    }
    __syncthreads();
    if (tid < NBUCK && cnt[tid] > 0) gpos[tid] = atomicAdd(&bcnt[tid], cnt[tid]);
    __syncthreads();
    for (int i = tid; i < n; i += 256) {
        int d = dst[base + i];
        int s = src[base + i];
        int b = d >> 9;
        int slot = atomicAdd(&lcur[b], 1);
        buf[loff[b] + slot] = (uint32)s | ((uint32)(d & 511) << 17);
    }
    __syncthreads();
    for (int i = tid; i < n; i += 256) {
        int lo = 0, hi = NBUCK;
        while (hi - lo > 1) { int mid = (lo + hi) >> 1; if (loff[mid] <= i) lo = mid; else hi = mid; }
        part[(size_t)lo * BCAP + gpos[lo] + (i - loff[lo])] = buf[i];
    }
}

// ---------------- build per-bucket CSR + col (in LDS) ----------------
__global__ __launch_bounds__(256) void build_col_kernel(
    const uint32* __restrict__ part, const int* __restrict__ bcnt,
    int* __restrict__ col, int2* __restrict__ rowpair) {
    __shared__ int ldeg[512];
    __shared__ int loffn[512];
    __shared__ int lcur[512];
    __shared__ int pscan[256];
    __shared__ int cl[BCAP];
    int b = blockIdx.x;
    int tid = threadIdx.x;
    int node0 = b << 9;
    int nn = min(node0 + 512, NN) - node0;
    int cnt = bcnt[b];
    int base = b * BCAP;
    const uint32* pp = part + (size_t)base;
    for (int i = tid; i < 512; i += 256) { ldeg[i] = 0; lcur[i] = 0; }
    __syncthreads();
    for (int i = tid; i < cnt; i += 256) atomicAdd(&ldeg[pp[i] >> 17], 1);
    __syncthreads();
    int t2 = tid * 2;
    int a0 = ldeg[t2], a1 = ldeg[t2 + 1];
    int ps = a0 + a1;
    pscan[tid] = ps;
    __syncthreads();
    for (int off = 1; off < 256; off <<= 1) {
        int v = (tid >= off) ? pscan[tid - off] : 0;
        __syncthreads();
        pscan[tid] += v;
        __syncthreads();
    }
    int eo = pscan[tid] - ps;
    loffn[t2] = eo;
    loffn[t2 + 1] = eo + a0;
    if (t2 < nn)     rowpair[node0 + t2]     = make_int2(base + eo, base + eo + a0);
    if (t2 + 1 < nn) rowpair[node0 + t2 + 1] = make_int2(base + eo + a0, base + eo + a0 + a1);
    __syncthreads();
    for (int i = tid; i < cnt; i += 256) {
        uint32 v = pp[i];
        int dl = (int)(v >> 17);
        int pos = atomicAdd(&lcur[dl], 1);
        cl[loffn[dl] + pos] = (int)(v & 0x1FFFFu);
    }
    __syncthreads();
    for (int i = tid; i < cnt; i += 256) col[base + i] = cl[i];
}

// ---------------- graph counts ----------------
__global__ void counts_kernel(const int* __restrict__ batch, float* __restrict__ cnt, int n) {
    __shared__ int h[GG];
    int tid = threadIdx.x;
    if (tid < GG) h[tid] = 0;
    __syncthreads();
    int i = blockIdx.x * 256 + tid;
    if (i < n) atomicAdd(&h[batch[i]], 1);
    __syncthreads();
    if (tid < GG && h[tid]) atomicAdd(&cnt[tid], (float)h[tid]);
}

// ---------------- x -> biased-uint8 row-quantized ----------------
// stored u = round(v*127/m) + 128; dequant sum: sum s*u - 128*sum s
__global__ void x_to_i8_kernel(const float* __restrict__ x, unsigned short* __restrict__ x8,
                               float* __restrict__ sc0) {
    int row = (blockIdx.x * 256 + threadIdx.x) >> 6;
    int lane = threadIdx.x & 63;
    if (row >= NN) return;
    float2 v = ((const float2*)x)[(size_t)row * 64 + lane];
    float m = fmaxf(fabsf(v.x), fabsf(v.y));
#pragma unroll
    for (int off = 1; off < 64; off <<= 1) m = fmaxf(m, __shfl_xor(m, off));
    float scale = m * (1.f / 127.f);
    float inv = (m > 0.f) ? 127.f / m : 0.f;
    int b0 = __float2int_rn(v.x * inv) + 128;
    int b1 = __float2int_rn(v.y * inv) + 128;
    unsigned short pk = (unsigned short)((b0 & 0xff) | ((b1 & 0xff) << 8));
    x8[(size_t)row * 64 + lane] = pk;
    if (lane == 0) sc0[row] = scale;
}

#define MAT_STRIDE 16384   // ushort elements per frag-ordered matrix

// frag-order weights: [br(2)][l(3)][mat(2)][nt(8)][ks(4)][lane(64)][j(8)]
__global__ void convert_w_kernel(const float* __restrict__ W1a, const float* __restrict__ W2a,
                                 const float* __restrict__ W1b, const float* __restrict__ W2b,
                                 unsigned short* __restrict__ out) {
    int t = blockIdx.x * 256 + threadIdx.x;
    if (t >= 24576) return;
    int lane = t & 63;
    int r = t >> 6;
    int ks = r & 3; r >>= 2;
    int nt = r & 7; r >>= 3;
    int mat = r & 1; r >>= 1;
    int l = r % 3, br = r / 3;
    const float* W = br ? (mat ? W2b : W1b) : (mat ? W2a : W1a);
    const float* Wl = W + (size_t)l * 128 * 128;
    int n0 = nt * 16 + (lane & 15);
    int k0 = ks * 32 + (lane >> 4) * 8;
    unsigned short tmp[8];
#pragma unroll
    for (int j = 0; j < 8; ++j) tmp[j] = f2bf(Wl[(size_t)(k0 + j) * 128 + n0]);
    size_t seq = (size_t)(br * 3 + l) * 2 + mat;
    size_t off = (((seq * 8 + nt) * 4 + ks) * 64 + (size_t)lane) * 8;
    *(uint4*)(out + off) = *(const uint4*)tmp;
}

// ---------------- BN coefs from replicated stats ----------------
__global__ void bn_coefs_kernel(const float* __restrict__ statsRep,
                                const float* __restrict__ ga, const float* __restrict__ bta,
                                const float* __restrict__ gb, const float* __restrict__ btb,
                                int l, float* __restrict__ coef) {
    int t = threadIdx.x;        // 256: br*128+cc
    int br = t >> 7, cc = t & 127;
    const float* base = statsRep + (size_t)((l * 2 + br) * NREP) * 256;
    float s = 0.f, sq = 0.f;
#pragma unroll
    for (int rep = 0; rep < NREP; ++rep) {
        s += base[rep * 256 + cc];
        sq += base[rep * 256 + 128 + cc];
    }
    float mu = s * (1.f / NN);
    float var = sq * (1.f / NN) - mu * mu;
    float gm = (br ? gb : ga)[l * 128 + cc];
    float A = gm * rsqrtf(var + BN_EPS);
    float B = (br ? btb : bta)[l * 128 + cc] - mu * A;
    coef[br * 256 + cc] = A;
    coef[br * 256 + 128 + cc] = B;
}

// ---------------- layer-0 gather on biased-u8 x ----------------
__global__ __launch_bounds__(256) void gather0_kernel(
    const unsigned char* __restrict__ x8b, const float* __restrict__ sc0,
    const int2* __restrict__ rowpair, const int* __restrict__ col,
    uint2* __restrict__ out) {
    int gw = (blockIdx.x * blockDim.x + threadIdx.x) >> 6;
    int lane = threadIdx.x & 63;
    if (gw >= NN) return;
    int slot = lane >> 5;
    int c = lane & 31;
    uint32 c4 = (uint32)c << 2;
    float4 accA = {0.f, 0.f, 0.f, 0.f};
    float4 accB = {0.f, 0.f, 0.f, 0.f};
    float S = 0.f;
    if (slot == 0) {
        float s = sc0[gw];
        uint32 u = ld32(x8b, ((uint32)gw << 7) + c4);
        accq(accA, u, s);
        S += s;
    }
    int2 be = rowpair[gw];
    int beg = be.x, end = be.y;
    for (int base = beg; base < end; base += 64) {
        int nb = min(64, end - base);
        int colv = col[base + min(lane, nb - 1)];
        int k = 0;
        for (; k + 4 <= nb; k += 4) {
            int j0 = __shfl(colv, k + slot);
            int j1 = __shfl(colv, k + 2 + slot);
            float s0 = ldf(sc0, (uint32)j0 << 2);
            float s1 = ldf(sc0, (uint32)j1 << 2);
            uint32 u0 = ld32(x8b, ((uint32)j0 << 7) + c4);
            uint32 u1 = ld32(x8b, ((uint32)j1 << 7) + c4);
            accq(accA, u0, s0); S += s0;
            accq(accB, u1, s1); S += s1;
        }
        for (; k + 2 <= nb; k += 2) {
            int j = __shfl(colv, k + slot);
            float s = ldf(sc0, (uint32)j << 2);
            uint32 u = ld32(x8b, ((uint32)j << 7) + c4);
            accq(accA, u, s); S += s;
        }
        if (k < nb) {
            int j = __shfl(colv, k);
            if (slot == 0) {
                float s = ldf(sc0, (uint32)j << 2);
                uint32 u = ld32(x8b, ((uint32)j << 7) + c4);
                accq(accA, u, s); S += s;
            }
        }
    }
    accA.x += accB.x; accA.y += accB.y; accA.z += accB.z; accA.w += accB.w;
    accA.x += __shfl_xor(accA.x, 32);
    accA.y += __shfl_xor(accA.y, 32);
    accA.z += __shfl_xor(accA.z, 32);
    accA.w += __shfl_xor(accA.w, 32);
    S += __shfl_xor(S, 32);
    float f0 = accA.x - 128.f * S;
    float f1 = accA.y - 128.f * S;
    float f2 = accA.z - 128.f * S;
    float f3 = accA.w - 128.f * S;
    if (slot == 0) {
        uint2 o;
        o.x = (uint32)f2bf(f0) | ((uint32)f2bf(f1) << 16);
        o.y = (uint32)f2bf(f2) | ((uint32)f2bf(f3) << 16);
        out[(uint32)gw * 32 + c] = o;
    }
}

// ---------------- dual-branch gather ----------------
__global__ __launch_bounds__(256) void gather_dual_kernel(
    const unsigned char* __restrict__ y8, const float* __restrict__ scales,
    const int2* __restrict__ rowpair, const int* __restrict__ col,
    const float* __restrict__ coef, uint2* __restrict__ out) {
    int gw = (blockIdx.x * blockDim.x + threadIdx.x) >> 6;
    int lane = threadIdx.x & 63;
    if (gw >= NN) return;
    int br = lane >> 5;
    int c32 = lane & 31;
    uint32 ln4 = (uint32)lane << 2;
    uint32 sb4 = (uint32)br << 2;
    float4 A4 = ((const float4*)(coef + br * 256))[c32];
    float4 B4 = ((const float4*)(coef + br * 256 + 128))[c32];
    float4 accA = {0.f, 0.f, 0.f, 0.f};
    float4 accB = {0.f, 0.f, 0.f, 0.f};
    {
        float s = ldf(scales, ((uint32)gw << 3) + sb4);
        uint32 u = ld32(y8, ((uint32)gw << 8) + ln4);
        accq(accA, u, s);
    }
    int2 be = rowpair[gw];
    int beg = be.x, end = be.y;
    float degp1 = (float)(end - beg + 1);
    for (int base = beg; base < end; base += 64) {
        int nb = min(64, end - base);
        int colv = col[base + min(lane, nb - 1)];
        int k = 0;
        for (; k + 4 <= nb; k += 4) {
            int j0 = __builtin_amdgcn_readlane(colv, k);
            int j1 = __builtin_amdgcn_readlane(colv, k + 1);
            int j2 = __builtin_amdgcn_readlane(colv, k + 2);
            int j3 = __builtin_amdgcn_readlane(colv, k + 3);
            float s0 = ldf(scales, ((uint32)j0 << 3) + sb4);
            float s1 = ldf(scales, ((uint32)j1 << 3) + sb4);
            float s2 = ldf(scales, ((uint32)j2 << 3) + sb4);
            float s3 = ldf(scales, ((uint32)j3 << 3) + sb4);
            uint32 u0 = ld32(y8, ((uint32)j0 << 8) + ln4);
            uint32 u1 = ld32(y8, ((uint32)j1 << 8) + ln4);
            uint32 u2 = ld32(y8, ((uint32)j2 << 8) + ln4);
            uint32 u3 = ld32(y8, ((uint32)j3 << 8) + ln4);
            accq(accA, u0, s0);
            accq(accB, u1, s1);
            accq(accA, u2, s2);
            accq(accB, u3, s3);
        }
        for (; k < nb; ++k) {
            int j = __builtin_amdgcn_readlane(colv, k);
            float s = ldf(scales, ((uint32)j << 3) + sb4);
            uint32 u = ld32(y8, ((uint32)j << 8) + ln4);
            accq(accA, u, s);
        }
    }
    float o0 = A4.x * (accA.x + accB.x) + B4.x * degp1;
    float o1 = A4.y * (accA.y + accB.y) + B4.y * degp1;
    float o2 = A4.z * (accA.z + accB.z) + B4.z * degp1;
    float o3 = A4.w * (accA.w + accB.w) + B4.w * degp1;
    uint2 o;
    o.x = (uint32)f2bf(o0) | ((uint32)f2bf(o1) << 16);
    o.y = (uint32)f2bf(o2) | ((uint32)f2bf(o3) << 16);
    out[(size_t)gw * 64 + lane] = o;
}

// ---------------- fused dual-branch MLP ----------------
// No W1 LDS stage (weights stream from L2 per-wave; same bytes, half the LDS).
// LDS = hs (34.8 KB) + stats (1 KB) -> 4 blocks/CU, 32 waves/CU.
// quant=0 (layer 2): pooled accumulation Sg[br][g][c] += sum h (replaces bufP+pool).
#define LDS_HS (8 * 16 * 136)
#define GSPAN 4
__global__ __launch_bounds__(512, 8) void mlp_dual_kernel(
    const unsigned short* __restrict__ X, int in_stride, int in_off_mul,
    const unsigned short* __restrict__ wf_all,
    const float* __restrict__ b1a, const float* __restrict__ b1b,
    const float* __restrict__ b2a, const float* __restrict__ b2b,
    int l, int quant,
    const int* __restrict__ batch, float* __restrict__ Sg,
    unsigned char* __restrict__ Y8,
    float* __restrict__ scales, float* __restrict__ statsRep, int n) {
    extern __shared__ unsigned short lds_all[];
    unsigned short (*hs)[16][136] = (unsigned short (*)[16][136])lds_all;
    float* ssum = (float*)(lds_all + LDS_HS);
    float* ssq = ssum + 128;

    int br = blockIdx.y;
    const unsigned short* Wf = wf_all + (size_t)(br * 3 + l) * 2 * MAT_STRIDE;
    const bf16x8* w1g = (const bf16x8*)Wf;
    const bf16x8* w2g = (const bf16x8*)(Wf + MAT_STRIDE);
    const float* b1 = (br ? b1b : b1a) + l * 128;
    const float* b2 = (br ? b2b : b2a) + l * 128;
    float* statsp = statsRep + (size_t)((l * 2 + br) * NREP + (blockIdx.x & (NREP - 1))) * 256;
    int in_off = in_off_mul * br;

    int tid = threadIdx.x;
    int wv = tid >> 6, lane = tid & 63;
    int quad = lane >> 4, l16 = lane & 15;

    int row0 = blockIdx.x * 128 + wv * 16;

    bf16x8 aF[4];
    {
        int r = row0 + l16;
        if (r >= n) r = n - 1;
        const unsigned short* xrow = X + (size_t)r * in_stride + in_off;
#pragma unroll
        for (int ks = 0; ks < 4; ++ks) aF[ks] = *(const bf16x8*)(xrow + ks * 32 + quad * 8);
    }

    if (tid < 128) { ssum[tid] = 0.f; ssq[tid] = 0.f; }
    __syncthreads();

    f32x4 acc1[8];
#pragma unroll
    for (int nt = 0; nt < 8; ++nt) {
        f32x4 c = {0.f, 0.f, 0.f, 0.f};
#pragma unroll
        for (int ks = 0; ks < 4; ++ks)
            c = __builtin_amdgcn_mfma_f32_16x16x32_bf16(aF[ks], w1g[(nt * 4 + ks) * 64 + lane], c, 0, 0, 0);
        acc1[nt] = c;
    }

#pragma unroll
    for (int nt = 0; nt < 8; ++nt) {
        int c0 = nt * 16 + l16;
        float bb = b1[c0];
#pragma unroll
        for (int r = 0; r < 4; ++r) {
            float v = fmaxf(acc1[nt][r] + bb, 0.f);
            hs[wv][quad * 4 + r][c0] = f2bf(v);
        }
    }

    bf16x8 aH[4];
#pragma unroll
    for (int ks = 0; ks < 4; ++ks)
        aH[ks] = *(const bf16x8*)(&hs[wv][l16][ks * 32 + quad * 8]);

    f32x4 acc2_[8];
#pragma unroll
    for (int nt = 0; nt < 8; ++nt) {
        f32x4 c = {0.f, 0.f, 0.f, 0.f};
        c = __builtin_amdgcn_mfma_f32_16x16x32_bf16(aH[0], w2g[(nt * 4 + 0) * 64 + lane], c, 0, 0, 0);
        c = __builtin_amdgcn_mfma_f32_16x16x32_bf16(aH[1], w2g[(nt * 4 + 1) * 64 + lane], c, 0, 0, 0);
        c = __builtin_amdgcn_mfma_f32_16x16x32_bf16(aH[2], w2g[(nt * 4 + 2) * 64 + lane], c, 0, 0, 0);
        c = __builtin_amdgcn_mfma_f32_16x16x32_bf16(aH[3], w2g[(nt * 4 + 3) * 64 + lane], c, 0, 0, 0);
        acc2_[nt] = c;
    }

#pragma unroll
    for (int nt = 0; nt < 8; ++nt) {
        int c0 = nt * 16 + l16;
        float bb = b2[c0];
        float s = 0.f, sq = 0.f;
#pragma unroll
        for (int r = 0; r < 4; ++r) {
            float v = fmaxf(acc2_[nt][r] + bb, 0.f);
            if (row0 + quad * 4 + r >= n) v = 0.f;
            acc2_[nt][r] = v;
            s += v; sq += v * v;
        }
        s += __shfl_xor(s, 16); s += __shfl_xor(s, 32);
        sq += __shfl_xor(sq, 16); sq += __shfl_xor(sq, 32);
        if (quad == 0) { atomicAdd(&ssum[c0], s); atomicAdd(&ssq[c0], sq); }
    }

    if (quant) {
        unsigned char* hs8 = (unsigned char*)&hs[wv][0][0];
#pragma unroll
        for (int r = 0; r < 4; ++r) {
            float m = acc2_[0][r];
#pragma unroll
            for (int nt = 1; nt < 8; ++nt) m = fmaxf(m, acc2_[nt][r]);
            m = fmaxf(m, __shfl_xor(m, 1));
            m = fmaxf(m, __shfl_xor(m, 2));
            m = fmaxf(m, __shfl_xor(m, 4));
            m = fmaxf(m, __shfl_xor(m, 8));
            float sc = m * (1.f / 255.f);
            float inv = (m > 0.f) ? 255.f / m : 0.f;
            int grow = row0 + quad * 4 + r;
            if (l16 == r && grow < n) scales[grow * 2 + br] = sc;
#pragma unroll
            for (int nt = 0; nt < 8; ++nt) {
                uint32 u = (uint32)__float2int_rn(acc2_[nt][r] * inv);
                hs8[(quad * 4 + r) * 144 + nt * 16 + l16] = (unsigned char)u;
            }
        }
        int grow = row0 + l16;
        if (grow < n) {
            *(uint4*)(Y8 + (size_t)grow * 256 + br * 128 + quad * 32) =
                *(const uint4*)(hs8 + l16 * 144 + quad * 32);
            *(uint4*)(Y8 + (size_t)grow * 256 + br * 128 + quad * 32 + 16) =
                *(const uint4*)(hs8 + l16 * 144 + quad * 32 + 16);
        }
    } else {
        // pooled accumulation: Sg[br][g][c] += sum over block rows of h
        __syncthreads();                       // hs dead for all waves after this
        float* pl = (float*)lds_all;           // GSPAN*128 floats
        for (int i = tid; i < GSPAN * 128; i += 512) pl[i] = 0.f;
        __syncthreads();
        int gmin = batch[blockIdx.x * 128];
        int gidx[4];
#pragma unroll
        for (int r = 0; r < 4; ++r) {
            int node = row0 + quad * 4 + r;
            int gi = -1;
            if (node < n) {
                gi = batch[node] - gmin;
                if (gi < 0) gi = 0;
                if (gi > GSPAN - 1) gi = GSPAN - 1;
            }
            gidx[r] = gi;
        }
#pragma unroll
        for (int nt = 0; nt < 8; ++nt) {
            int c0 = nt * 16 + l16;
#pragma unroll
            for (int r = 0; r < 4; ++r)
                if (gidx[r] >= 0) atomicAdd(&pl[gidx[r] * 128 + c0], acc2_[nt][r]);
        }
        __syncthreads();
        for (int i = tid; i < GSPAN * 128; i += 512) {
            float v = pl[i];
            int g = gmin + (i >> 7);
            if (v != 0.f && g < GG)
                atomicAdd(&Sg[(size_t)br * GG * 128 + g * 128 + (i & 127)], v);
        }
    }
    __syncthreads();
    if (tid < 128) {
        atomicAdd(&statsp[tid], ssum[tid]);
        atomicAdd(&statsp[128 + tid], ssq[tid]);
    }
}

// ---------------- bilinear discriminator (from raw pooled sums) ----------------
__global__ void disc_kernel(const float* __restrict__ Sg, const float* __restrict__ cnt,
                            const float* __restrict__ coefL2,
                            const float* __restrict__ W, const float* __restrict__ db,
                            float* __restrict__ out) {
    int g = blockIdx.x, e = threadIdx.x;
    __shared__ float pg[128], ps[128], rs[128], rh[128];
    float invc = 1.f / fmaxf(cnt[g], 1.f);
    int gs = (g == 32) ? 30 : (63 - g);
    float invcs = 1.f / fmaxf(cnt[gs], 1.f);
    float Ab = coefL2[256 + e], Bb = coefL2[384 + e];
    const float* SB = Sg + (size_t)GG * 128;
    pg[e] = Ab * SB[g * 128 + e] + Bb * cnt[g];
    ps[e] = Ab * SB[gs * 128 + e] + Bb * cnt[gs];
    __syncthreads();
    float t = 0.f;
    for (int d = 0; d < 128; ++d) t += pg[d] * W[d * 128 + e];
    t *= invc;
    rs[e] = t * pg[e] * invc;
    rh[e] = t * ps[e] * invcs;
    __syncthreads();
    for (int s = 64; s > 0; s >>= 1) {
        if (e < s) { rs[e] += rs[e + s]; rh[e] += rh[e + s]; }
        __syncthreads();
    }
    if (e == 0) {
        out[GG * 10 + g] = rs[0] + db[0];
        out[GG * 10 + GG + g] = rh[0] + db[0];
    }
}

// ---------------- classification head (from raw pooled sums) ----------------
__global__ void head_kernel(const float* __restrict__ Sg, const float* __restrict__ cnt,
                            const float* __restrict__ coefL2,
                            const float* __restrict__ w1, const float* __restrict__ b1,
                            const float* __restrict__ w2, const float* __restrict__ b2,
                            float* __restrict__ out) {
    int g = blockIdx.x, j = threadIdx.x;
    __shared__ float ma[128], px[128];
    __shared__ float s1[128];
    __shared__ float s2[10];
    __shared__ float lse;
    float cg = cnt[g];
    float invc = 1.f / fmaxf(cg, 1.f);
    float Aa = coefL2[j],       Ba = coefL2[128 + j];
    float Ab = coefL2[256 + j], Bb = coefL2[384 + j];
    ma[j] = (Aa * Sg[g * 128 + j] + Ba * cg) * invc;
    px[j] = (Ab * Sg[(size_t)GG * 128 + g * 128 + j] + Bb * cg) * invc;
    __syncthreads();
    float acc = b1[j];
    for (int k = 0; k < 128; ++k) acc += ma[k] * w1[k * 128 + j];
    for (int k = 0; k < 128; ++k) acc += px[k] * w1[(128 + k) * 128 + j];
    s1[j] = fmaxf(acc, 0.f);
    __syncthreads();
    if (j < 10) {
        float a = b2[j];
        for (int k = 0; k < 128; ++k) a += s1[k] * w2[k * 10 + j];
        s2[j] = a;
    }
    __syncthreads();
    if (j == 0) {
        float m = s2[0];
        for (int o = 1; o < 10; ++o) m = fmaxf(m, s2[o]);
        float se = 0.f;
        for (int o = 0; o < 10; ++o) se += expf(s2[o] - m);
        lse = m + logf(se);
    }
    __syncthreads();
    if (j < 10) out[g * 10 + j] = s2[j] - lse;
}

extern "C" void kernel_launch(void* const* d_in, const int* in_sizes, int n_in,
                              void* d_out, int out_size, void* d_ws, size_t ws_size,
                              hipStream_t stream) {
    const float* x     = (const float*)d_in[0];
    const int*   ei    = (const int*)d_in[1];
    const int*   batch = (const int*)d_in[2];
    const float* W1a = (const float*)d_in[3];
    const float* b1a = (const float*)d_in[4];
    const float* W2a = (const float*)d_in[5];
    const float* b2a = (const float*)d_in[6];
    const float* ga  = (const float*)d_in[7];
    const float* bta = (const float*)d_in[8];
    const float* W1b = (const float*)d_in[9];
    const float* b1b = (const float*)d_in[10];
    const float* W2b = (const float*)d_in[11];
    const float* b2b = (const float*)d_in[12];
    const float* gb  = (const float*)d_in[13];
    const float* btb = (const float*)d_in[14];
    const float* lin1_w = (const float*)d_in[15];
    const float* lin1_b = (const float*)d_in[16];
    const float* lin2_w = (const float*)d_in[17];
    const float* lin2_b = (const float*)d_in[18];
    const float* disc_w = (const float*)d_in[19];
    const float* disc_b = (const float*)d_in[20];
    float* out = (float*)d_out;

    const int* src = ei;
    const int* dst = ei + EE;

    size_t o = 0;
    auto take = [&](size_t b) { size_t p = o; o = (o + b + 255) & ~(size_t)255; return p; };
    uint8_t* w = (uint8_t*)d_ws;
    size_t o_x8   = take((size_t)NN * 128);
    size_t o_sc0  = take((size_t)NN * 4);
    size_t o_g0   = take((size_t)NN * 128 * 2);
    size_t o_gbuf = take((size_t)NN * 256 * 2);
    size_t o_y8a  = take((size_t)NN * 256);
    size_t o_y8b  = take((size_t)NN * 256);
    size_t o_scA  = take((size_t)NN * 2 * 4);
    size_t o_scB  = take((size_t)NN * 2 * 4);
    size_t o_wf   = take((size_t)12 * MAT_STRIDE * 2);
    size_t o_col  = take((size_t)NBUCK * BCAP * 4);
    size_t o_part = take((size_t)NBUCK * BCAP * 4);
    size_t o_rowpair = take((size_t)NN * 8);
    size_t o_coef = take((size_t)3 * 2 * 256 * 4);
    size_t zero_begin = o;
    size_t o_bcnt   = take((size_t)NBUCK * 4);
    size_t o_stats  = take((size_t)6 * NREP * 256 * 4);
    size_t o_cnt    = take(GG * 4);
    size_t o_Sg     = take((size_t)2 * GG * 128 * 4);
    size_t zero_end = o;

    unsigned short* x8 = (unsigned short*)(w + o_x8);
    float* sc0 = (float*)(w + o_sc0);
    uint32* g0 = (uint32*)(w + o_g0);
    unsigned short* gbuf = (unsigned short*)(w + o_gbuf);
    unsigned char* y8a = (unsigned char*)(w + o_y8a);
    unsigned char* y8b = (unsigned char*)(w + o_y8b);
    float* scA = (float*)(w + o_scA);
    float* scB = (float*)(w + o_scB);
    unsigned short* wf = (unsigned short*)(w + o_wf);
    int* col = (int*)(w + o_col);
    uint32* part = (uint32*)(w + o_part);
    int2* rowpair = (int2*)(w + o_rowpair);
    float* coef = (float*)(w + o_coef);
    int* bcnt = (int*)(w + o_bcnt);
    float* statsRep = (float*)(w + o_stats);
    float* cnt = (float*)(w + o_cnt);
    float* Sg = (float*)(w + o_Sg);

    hipMemsetAsync(w + zero_begin, 0, zero_end - zero_begin, stream);

    x_to_i8_kernel<<<(NN * 64 + 255) / 256, 256, 0, stream>>>(x, x8, sc0);
    convert_w_kernel<<<(24576 + 255) / 256, 256, 0, stream>>>(W1a, W2a, W1b, W2b, wf);

    partition_kernel<<<(EE + PART_CHUNK - 1) / PART_CHUNK, 256, 0, stream>>>(src, dst, bcnt, part);
    build_col_kernel<<<NBUCK, 256, 0, stream>>>(part, bcnt, col, rowpair);
    counts_kernel<<<(NN + 255) / 256, 256, 0, stream>>>(batch, cnt, NN);

    int gatherBlocks = (NN + 3) / 4;
    dim3 mlpGrid((NN + 127) / 128, 2);
    size_t ldsBytes = (size_t)LDS_HS * 2 + 256 * 4;  // 35840

    gather0_kernel<<<gatherBlocks, 256, 0, stream>>>(
        (const unsigned char*)x8, sc0, rowpair, col, (uint2*)g0);

    // layer 0: g0 -> y8a
    mlp_dual_kernel<<<mlpGrid, 512, ldsBytes, stream>>>(
        (const unsigned short*)g0, 128, 0, wf, b1a, b1b, b2a, b2b, 0, 1,
        batch, Sg, y8a, scA, statsRep, NN);
    bn_coefs_kernel<<<1, 256, 0, stream>>>(statsRep, ga, bta, gb, btb, 0, coef + 0 * 512);

    // layer 1: gather(y8a) -> gbuf; mlp -> y8b
    gather_dual_kernel<<<gatherBlocks, 256, 0, stream>>>(
        y8a, scA, rowpair, col, coef + 0 * 512, (uint2*)gbuf);
    mlp_dual_kernel<<<mlpGrid, 512, ldsBytes, stream>>>(
        gbuf, 256, 128, wf, b1a, b1b, b2a, b2b, 1, 1,
        batch, Sg, y8b, scB, statsRep, NN);
    bn_coefs_kernel<<<1, 256, 0, stream>>>(statsRep, ga, bta, gb, btb, 1, coef + 1 * 512);

    // layer 2: gather(y8b) -> gbuf; mlp -> pooled sums Sg (no bufP, no pool kernel)
    gather_dual_kernel<<<gatherBlocks, 256, 0, stream>>>(
        y8b, scB, rowpair, col, coef + 1 * 512, (uint2*)gbuf);
    mlp_dual_kernel<<<mlpGrid, 512, ldsBytes, stream>>>(
        gbuf, 256, 128, wf, b1a, b1b, b2a, b2b, 2, 0,
        batch, Sg, nullptr, nullptr, statsRep, NN);
    bn_coefs_kernel<<<1, 256, 0, stream>>>(statsRep, ga, bta, gb, btb, 2, coef + 2 * 512);

    disc_kernel<<<GG, 128, 0, stream>>>(Sg, cnt, coef + 2 * 512, disc_w, disc_b, out);
    head_kernel<<<GG, 128, 0, stream>>>(Sg, cnt, coef + 2 * 512, lin1_w, lin1_b, lin2_w, lin2_b, out);
}

// Round 7
// 745.450 us; speedup vs baseline: 1.0118x; 1.0118x over previous
//
#include <hip/hip_runtime.h>
#include <hip/hip_bf16.h>

#define NN 100000
#define EE 1600000
#define GG 64
#define HH 128
#define LL 3
#define BN_EPS 1e-5f
#define NBUCK 196          // ceil(NN/512)
#define BCAP 12288         // bucket capacity (mean 8163, +45 sigma safe)
#define PART_CHUNK 8192
#define NREP 16            // stats replicas

typedef __attribute__((ext_vector_type(8))) short bf16x8;
typedef __attribute__((ext_vector_type(4))) float f32x4;
typedef unsigned int uint32;

__device__ __forceinline__ unsigned short f2bf(float f) {
    uint32 x = __float_as_uint(f);
    uint32 r = (x + 0x7fffu + ((x >> 16) & 1u)) >> 16;
    return (unsigned short)r;
}
__device__ __forceinline__ float bf2f(unsigned short u) { return __uint_as_float(((uint32)u) << 16); }
// dequant-accumulate 4 unsigned uint8 channels with per-row scale
__device__ __forceinline__ void accq(float4& a, uint32 u, float sc) {
    a.x += sc * (float)(u & 0xffu);
    a.y += sc * (float)((u >> 8) & 0xffu);
    a.z += sc * (float)((u >> 16) & 0xffu);
    a.w += sc * (float)(u >> 24);
}
__device__ __forceinline__ uint32 ld32(const unsigned char* p, uint32 off) {
    return *(const uint32*)(p + off);
}
__device__ __forceinline__ float ldf(const float* p, uint32 byteoff) {
    return *(const float*)((const char*)p + byteoff);
}

// ---------------- bucketed edge partition ----------------
__global__ __launch_bounds__(256) void partition_kernel(
    const int* __restrict__ src, const int* __restrict__ dst,
    int* __restrict__ bcnt, uint32* __restrict__ part) {
    __shared__ int cnt[NBUCK];
    __shared__ int loff[NBUCK + 1];
    __shared__ int gpos[NBUCK];
    __shared__ int lcur[NBUCK];
    __shared__ uint32 buf[PART_CHUNK];
    int tid = threadIdx.x;
    int base = blockIdx.x * PART_CHUNK;
    int n = min(PART_CHUNK, EE - base);
    for (int i = tid; i < NBUCK; i += 256) { cnt[i] = 0; lcur[i] = 0; }
    __syncthreads();
    for (int i = tid; i < n; i += 256) atomicAdd(&cnt[dst[base + i] >> 9], 1);
    __syncthreads();
    if (tid == 0) {
        int acc = 0;
        for (int b = 0; b < NBUCK; ++b) { loff[b] = acc; acc += cnt[b]; }
        loff[NBUCK] = acc;
    }
    __syncthreads();
    if (tid < NBUCK && cnt[tid] > 0) gpos[tid] = atomicAdd(&bcnt[tid], cnt[tid]);
    __syncthreads();
    for (int i = tid; i < n; i += 256) {
        int d = dst[base + i];
        int s = src[base + i];
        int b = d >> 9;
        int slot = atomicAdd(&lcur[b], 1);
        buf[loff[b] + slot] = (uint32)s | ((uint32)(d & 511) << 17);
    }
    __syncthreads();
    for (int i = tid; i < n; i += 256) {
        int lo = 0, hi = NBUCK;
        while (hi - lo > 1) { int mid = (lo + hi) >> 1; if (loff[mid] <= i) lo = mid; else hi = mid; }
        part[(size_t)lo * BCAP + gpos[lo] + (i - loff[lo])] = buf[i];
    }
}

// ---------------- build per-bucket CSR + col (in LDS) ----------------
__global__ __launch_bounds__(256) void build_col_kernel(
    const uint32* __restrict__ part, const int* __restrict__ bcnt,
    int* __restrict__ col, int2* __restrict__ rowpair) {
    __shared__ int ldeg[512];
    __shared__ int loffn[512];
    __shared__ int lcur[512];
    __shared__ int pscan[256];
    __shared__ int cl[BCAP];
    int b = blockIdx.x;
    int tid = threadIdx.x;
    int node0 = b << 9;
    int nn = min(node0 + 512, NN) - node0;
    int cnt = bcnt[b];
    int base = b * BCAP;
    const uint32* pp = part + (size_t)base;
    for (int i = tid; i < 512; i += 256) { ldeg[i] = 0; lcur[i] = 0; }
    __syncthreads();
    for (int i = tid; i < cnt; i += 256) atomicAdd(&ldeg[pp[i] >> 17], 1);
    __syncthreads();
    int t2 = tid * 2;
    int a0 = ldeg[t2], a1 = ldeg[t2 + 1];
    int ps = a0 + a1;
    pscan[tid] = ps;
    __syncthreads();
    for (int off = 1; off < 256; off <<= 1) {
        int v = (tid >= off) ? pscan[tid - off] : 0;
        __syncthreads();
        pscan[tid] += v;
        __syncthreads();
    }
    int eo = pscan[tid] - ps;
    loffn[t2] = eo;
    loffn[t2 + 1] = eo + a0;
    if (t2 < nn)     rowpair[node0 + t2]     = make_int2(base + eo, base + eo + a0);
    if (t2 + 1 < nn) rowpair[node0 + t2 + 1] = make_int2(base + eo + a0, base + eo + a0 + a1);
    __syncthreads();
    for (int i = tid; i < cnt; i += 256) {
        uint32 v = pp[i];
        int dl = (int)(v >> 17);
        int pos = atomicAdd(&lcur[dl], 1);
        cl[loffn[dl] + pos] = (int)(v & 0x1FFFFu);
    }
    __syncthreads();
    for (int i = tid; i < cnt; i += 256) col[base + i] = cl[i];
}

// ---------------- graph counts ----------------
__global__ void counts_kernel(const int* __restrict__ batch, float* __restrict__ cnt, int n) {
    __shared__ int h[GG];
    int tid = threadIdx.x;
    if (tid < GG) h[tid] = 0;
    __syncthreads();
    int i = blockIdx.x * 256 + tid;
    if (i < n) atomicAdd(&h[batch[i]], 1);
    __syncthreads();
    if (tid < GG && h[tid]) atomicAdd(&cnt[tid], (float)h[tid]);
}

// ---------------- x -> biased-uint8 row-quantized ----------------
// stored u = round(v*127/m) + 128; dequant sum: sum s*u - 128*sum s
__global__ void x_to_i8_kernel(const float* __restrict__ x, unsigned short* __restrict__ x8,
                               float* __restrict__ sc0) {
    int row = (blockIdx.x * 256 + threadIdx.x) >> 6;
    int lane = threadIdx.x & 63;
    if (row >= NN) return;
    float2 v = ((const float2*)x)[(size_t)row * 64 + lane];
    float m = fmaxf(fabsf(v.x), fabsf(v.y));
#pragma unroll
    for (int off = 1; off < 64; off <<= 1) m = fmaxf(m, __shfl_xor(m, off));
    float scale = m * (1.f / 127.f);
    float inv = (m > 0.f) ? 127.f / m : 0.f;
    int b0 = __float2int_rn(v.x * inv) + 128;
    int b1 = __float2int_rn(v.y * inv) + 128;
    unsigned short pk = (unsigned short)((b0 & 0xff) | ((b1 & 0xff) << 8));
    x8[(size_t)row * 64 + lane] = pk;
    if (lane == 0) sc0[row] = scale;
}

#define MAT_STRIDE 16384   // ushort elements per frag-ordered matrix

// frag-order weights: [br(2)][l(3)][mat(2)][nt(8)][ks(4)][lane(64)][j(8)]
__global__ void convert_w_kernel(const float* __restrict__ W1a, const float* __restrict__ W2a,
                                 const float* __restrict__ W1b, const float* __restrict__ W2b,
                                 unsigned short* __restrict__ out) {
    int t = blockIdx.x * 256 + threadIdx.x;
    if (t >= 24576) return;
    int lane = t & 63;
    int r = t >> 6;
    int ks = r & 3; r >>= 2;
    int nt = r & 7; r >>= 3;
    int mat = r & 1; r >>= 1;
    int l = r % 3, br = r / 3;
    const float* W = br ? (mat ? W2b : W1b) : (mat ? W2a : W1a);
    const float* Wl = W + (size_t)l * 128 * 128;
    int n0 = nt * 16 + (lane & 15);
    int k0 = ks * 32 + (lane >> 4) * 8;
    unsigned short tmp[8];
#pragma unroll
    for (int j = 0; j < 8; ++j) tmp[j] = f2bf(Wl[(size_t)(k0 + j) * 128 + n0]);
    size_t seq = (size_t)(br * 3 + l) * 2 + mat;
    size_t off = (((seq * 8 + nt) * 4 + ks) * 64 + (size_t)lane) * 8;
    *(uint4*)(out + off) = *(const uint4*)tmp;
}

// ---------------- BN coefs from replicated stats ----------------
__global__ void bn_coefs_kernel(const float* __restrict__ statsRep,
                                const float* __restrict__ ga, const float* __restrict__ bta,
                                const float* __restrict__ gb, const float* __restrict__ btb,
                                int l, float* __restrict__ coef) {
    int t = threadIdx.x;        // 256: br*128+cc
    int br = t >> 7, cc = t & 127;
    const float* base = statsRep + (size_t)((l * 2 + br) * NREP) * 256;
    float s = 0.f, sq = 0.f;
#pragma unroll
    for (int rep = 0; rep < NREP; ++rep) {
        s += base[rep * 256 + cc];
        sq += base[rep * 256 + 128 + cc];
    }
    float mu = s * (1.f / NN);
    float var = sq * (1.f / NN) - mu * mu;
    float gm = (br ? gb : ga)[l * 128 + cc];
    float A = gm * rsqrtf(var + BN_EPS);
    float B = (br ? btb : bta)[l * 128 + cc] - mu * A;
    coef[br * 256 + cc] = A;
    coef[br * 256 + 128 + cc] = B;
}

// ---------------- layer-0 gather on biased-u8 x ----------------
__global__ __launch_bounds__(256) void gather0_kernel(
    const unsigned char* __restrict__ x8b, const float* __restrict__ sc0,
    const int2* __restrict__ rowpair, const int* __restrict__ col,
    uint2* __restrict__ out) {
    int gw = (blockIdx.x * blockDim.x + threadIdx.x) >> 6;
    int lane = threadIdx.x & 63;
    if (gw >= NN) return;
    int slot = lane >> 5;
    int c = lane & 31;
    uint32 c4 = (uint32)c << 2;
    float4 accA = {0.f, 0.f, 0.f, 0.f};
    float4 accB = {0.f, 0.f, 0.f, 0.f};
    float S = 0.f;
    if (slot == 0) {
        float s = sc0[gw];
        uint32 u = ld32(x8b, ((uint32)gw << 7) + c4);
        accq(accA, u, s);
        S += s;
    }
    int2 be = rowpair[gw];
    int beg = be.x, end = be.y;
    for (int base = beg; base < end; base += 64) {
        int nb = min(64, end - base);
        int colv = col[base + min(lane, nb - 1)];
        int k = 0;
        for (; k + 4 <= nb; k += 4) {
            int j0 = __shfl(colv, k + slot);
            int j1 = __shfl(colv, k + 2 + slot);
            float s0 = ldf(sc0, (uint32)j0 << 2);
            float s1 = ldf(sc0, (uint32)j1 << 2);
            uint32 u0 = ld32(x8b, ((uint32)j0 << 7) + c4);
            uint32 u1 = ld32(x8b, ((uint32)j1 << 7) + c4);
            accq(accA, u0, s0); S += s0;
            accq(accB, u1, s1); S += s1;
        }
        for (; k + 2 <= nb; k += 2) {
            int j = __shfl(colv, k + slot);
            float s = ldf(sc0, (uint32)j << 2);
            uint32 u = ld32(x8b, ((uint32)j << 7) + c4);
            accq(accA, u, s); S += s;
        }
        if (k < nb) {
            int j = __shfl(colv, k);
            if (slot == 0) {
                float s = ldf(sc0, (uint32)j << 2);
                uint32 u = ld32(x8b, ((uint32)j << 7) + c4);
                accq(accA, u, s); S += s;
            }
        }
    }
    accA.x += accB.x; accA.y += accB.y; accA.z += accB.z; accA.w += accB.w;
    accA.x += __shfl_xor(accA.x, 32);
    accA.y += __shfl_xor(accA.y, 32);
    accA.z += __shfl_xor(accA.z, 32);
    accA.w += __shfl_xor(accA.w, 32);
    S += __shfl_xor(S, 32);
    float f0 = accA.x - 128.f * S;
    float f1 = accA.y - 128.f * S;
    float f2 = accA.z - 128.f * S;
    float f3 = accA.w - 128.f * S;
    if (slot == 0) {
        uint2 o;
        o.x = (uint32)f2bf(f0) | ((uint32)f2bf(f1) << 16);
        o.y = (uint32)f2bf(f2) | ((uint32)f2bf(f3) << 16);
        out[(uint32)gw * 32 + c] = o;
    }
}

// ---------------- dual-branch gather ----------------
__global__ __launch_bounds__(256) void gather_dual_kernel(
    const unsigned char* __restrict__ y8, const float* __restrict__ scales,
    const int2* __restrict__ rowpair, const int* __restrict__ col,
    const float* __restrict__ coef, uint2* __restrict__ out) {
    int gw = (blockIdx.x * blockDim.x + threadIdx.x) >> 6;
    int lane = threadIdx.x & 63;
    if (gw >= NN) return;
    int br = lane >> 5;
    int c32 = lane & 31;
    uint32 ln4 = (uint32)lane << 2;
    uint32 sb4 = (uint32)br << 2;
    float4 A4 = ((const float4*)(coef + br * 256))[c32];
    float4 B4 = ((const float4*)(coef + br * 256 + 128))[c32];
    float4 accA = {0.f, 0.f, 0.f, 0.f};
    float4 accB = {0.f, 0.f, 0.f, 0.f};
    {
        float s = ldf(scales, ((uint32)gw << 3) + sb4);
        uint32 u = ld32(y8, ((uint32)gw << 8) + ln4);
        accq(accA, u, s);
    }
    int2 be = rowpair[gw];
    int beg = be.x, end = be.y;
    float degp1 = (float)(end - beg + 1);
    for (int base = beg; base < end; base += 64) {
        int nb = min(64, end - base);
        int colv = col[base + min(lane, nb - 1)];
        int k = 0;
        for (; k + 4 <= nb; k += 4) {
            int j0 = __builtin_amdgcn_readlane(colv, k);
            int j1 = __builtin_amdgcn_readlane(colv, k + 1);
            int j2 = __builtin_amdgcn_readlane(colv, k + 2);
            int j3 = __builtin_amdgcn_readlane(colv, k + 3);
            float s0 = ldf(scales, ((uint32)j0 << 3) + sb4);
            float s1 = ldf(scales, ((uint32)j1 << 3) + sb4);
            float s2 = ldf(scales, ((uint32)j2 << 3) + sb4);
            float s3 = ldf(scales, ((uint32)j3 << 3) + sb4);
            uint32 u0 = ld32(y8, ((uint32)j0 << 8) + ln4);
            uint32 u1 = ld32(y8, ((uint32)j1 << 8) + ln4);
            uint32 u2 = ld32(y8, ((uint32)j2 << 8) + ln4);
            uint32 u3 = ld32(y8, ((uint32)j3 << 8) + ln4);
            accq(accA, u0, s0);
            accq(accB, u1, s1);
            accq(accA, u2, s2);
            accq(accB, u3, s3);
        }
        for (; k < nb; ++k) {
            int j = __builtin_amdgcn_readlane(colv, k);
            float s = ldf(scales, ((uint32)j << 3) + sb4);
            uint32 u = ld32(y8, ((uint32)j << 8) + ln4);
            accq(accA, u, s);
        }
    }
    float o0 = A4.x * (accA.x + accB.x) + B4.x * degp1;
    float o1 = A4.y * (accA.y + accB.y) + B4.y * degp1;
    float o2 = A4.z * (accA.z + accB.z) + B4.z * degp1;
    float o3 = A4.w * (accA.w + accB.w) + B4.w * degp1;
    uint2 o;
    o.x = (uint32)f2bf(o0) | ((uint32)f2bf(o1) << 16);
    o.y = (uint32)f2bf(o2) | ((uint32)f2bf(o3) << 16);
    out[(size_t)gw * 64 + lane] = o;
}

// ---------------- fused dual-branch MLP (round-5 body): 512 threads, W1 LDS stage --------
// quant=0 (layer 2): pooled accumulation Sg[br][g][c] += sum h (replaces bufP+pool),
// reusing the dead W1 LDS region for the per-block pool scratch.
#define LDS_W1 16384
#define LDS_HS (8 * 16 * 136)
#define GSPAN 4
__global__ __launch_bounds__(512, 4) void mlp_dual_kernel(
    const unsigned short* __restrict__ X, int in_stride, int in_off_mul,
    const unsigned short* __restrict__ wf_all,
    const float* __restrict__ b1a, const float* __restrict__ b1b,
    const float* __restrict__ b2a, const float* __restrict__ b2b,
    int l, int quant,
    const int* __restrict__ batch, float* __restrict__ Sg,
    unsigned char* __restrict__ Y8,
    float* __restrict__ scales, float* __restrict__ statsRep, int n) {
    extern __shared__ unsigned short lds_all[];
    unsigned short* w1s = lds_all;
    unsigned short (*hs)[16][136] = (unsigned short (*)[16][136])(lds_all + LDS_W1);
    float* ssum = (float*)(lds_all + LDS_W1 + LDS_HS);
    float* ssq = ssum + 128;

    int br = blockIdx.y;
    const unsigned short* Wf = wf_all + (size_t)(br * 3 + l) * 2 * MAT_STRIDE;
    const float* b1 = (br ? b1b : b1a) + l * 128;
    const float* b2 = (br ? b2b : b2a) + l * 128;
    float* statsp = statsRep + (size_t)((l * 2 + br) * NREP + (blockIdx.x & (NREP - 1))) * 256;
    int in_off = in_off_mul * br;

    int tid = threadIdx.x;
    int wv = tid >> 6, lane = tid & 63;
    int quad = lane >> 4, l16 = lane & 15;

    const bf16x8* w2g = (const bf16x8*)(Wf + MAT_STRIDE);

    bf16x8 w2p[2][4];
#pragma unroll
    for (int p = 0; p < 2; ++p)
#pragma unroll
        for (int ks = 0; ks < 4; ++ks) w2p[p][ks] = w2g[(p * 4 + ks) * 64 + lane];

    int row0 = blockIdx.x * 128 + wv * 16;

    bf16x8 aF[4];
    {
        int r = row0 + l16;
        if (r >= n) r = n - 1;
        const unsigned short* xrow = X + (size_t)r * in_stride + in_off;
#pragma unroll
        for (int ks = 0; ks < 4; ++ks) aF[ks] = *(const bf16x8*)(xrow + ks * 32 + quad * 8);
    }

    {
        const uint4* srcp = (const uint4*)Wf;
        uint4* dstp = (uint4*)w1s;
        for (int i = tid; i < 2048; i += 512) dstp[i] = srcp[i];
    }
    if (tid < 128) { ssum[tid] = 0.f; ssq[tid] = 0.f; }
    __syncthreads();

    f32x4 acc1[8];
#pragma unroll
    for (int nt = 0; nt < 8; ++nt) {
        f32x4 c = {0.f, 0.f, 0.f, 0.f};
#pragma unroll
        for (int ks = 0; ks < 4; ++ks) {
            bf16x8 bfrag = *(const bf16x8*)(&w1s[((nt * 4 + ks) * 64 + lane) * 8]);
            c = __builtin_amdgcn_mfma_f32_16x16x32_bf16(aF[ks], bfrag, c, 0, 0, 0);
        }
        acc1[nt] = c;
    }

#pragma unroll
    for (int nt = 0; nt < 8; ++nt) {
        int c0 = nt * 16 + l16;
        float bb = b1[c0];
#pragma unroll
        for (int r = 0; r < 4; ++r) {
            float v = fmaxf(acc1[nt][r] + bb, 0.f);
            hs[wv][quad * 4 + r][c0] = f2bf(v);
        }
    }

    bf16x8 aH[4];
#pragma unroll
    for (int ks = 0; ks < 4; ++ks)
        aH[ks] = *(const bf16x8*)(&hs[wv][l16][ks * 32 + quad * 8]);

    f32x4 acc2_[8];
#pragma unroll
    for (int nt = 0; nt < 8; ++nt) {
        bf16x8 bf0, bf1, bf2, bf3;
        if (nt < 2) { bf0 = w2p[nt][0]; bf1 = w2p[nt][1]; bf2 = w2p[nt][2]; bf3 = w2p[nt][3]; }
        else {
            bf0 = w2g[(nt * 4 + 0) * 64 + lane];
            bf1 = w2g[(nt * 4 + 1) * 64 + lane];
            bf2 = w2g[(nt * 4 + 2) * 64 + lane];
            bf3 = w2g[(nt * 4 + 3) * 64 + lane];
        }
        f32x4 c = {0.f, 0.f, 0.f, 0.f};
        c = __builtin_amdgcn_mfma_f32_16x16x32_bf16(aH[0], bf0, c, 0, 0, 0);
        c = __builtin_amdgcn_mfma_f32_16x16x32_bf16(aH[1], bf1, c, 0, 0, 0);
        c = __builtin_amdgcn_mfma_f32_16x16x32_bf16(aH[2], bf2, c, 0, 0, 0);
        c = __builtin_amdgcn_mfma_f32_16x16x32_bf16(aH[3], bf3, c, 0, 0, 0);
        acc2_[nt] = c;
    }

#pragma unroll
    for (int nt = 0; nt < 8; ++nt) {
        int c0 = nt * 16 + l16;
        float bb = b2[c0];
        float s = 0.f, sq = 0.f;
#pragma unroll
        for (int r = 0; r < 4; ++r) {
            float v = fmaxf(acc2_[nt][r] + bb, 0.f);
            if (row0 + quad * 4 + r >= n) v = 0.f;
            acc2_[nt][r] = v;
            s += v; sq += v * v;
        }
        s += __shfl_xor(s, 16); s += __shfl_xor(s, 32);
        sq += __shfl_xor(sq, 16); sq += __shfl_xor(sq, 32);
        if (quad == 0) { atomicAdd(&ssum[c0], s); atomicAdd(&ssq[c0], sq); }
    }

    if (quant) {
        unsigned char* hs8 = (unsigned char*)&hs[wv][0][0];
#pragma unroll
        for (int r = 0; r < 4; ++r) {
            float m = acc2_[0][r];
#pragma unroll
            for (int nt = 1; nt < 8; ++nt) m = fmaxf(m, acc2_[nt][r]);
            m = fmaxf(m, __shfl_xor(m, 1));
            m = fmaxf(m, __shfl_xor(m, 2));
            m = fmaxf(m, __shfl_xor(m, 4));
            m = fmaxf(m, __shfl_xor(m, 8));
            float sc = m * (1.f / 255.f);
            float inv = (m > 0.f) ? 255.f / m : 0.f;
            int grow = row0 + quad * 4 + r;
            if (l16 == r && grow < n) scales[grow * 2 + br] = sc;
#pragma unroll
            for (int nt = 0; nt < 8; ++nt) {
                uint32 u = (uint32)__float2int_rn(acc2_[nt][r] * inv);
                hs8[(quad * 4 + r) * 144 + nt * 16 + l16] = (unsigned char)u;
            }
        }
        int grow = row0 + l16;
        if (grow < n) {
            *(uint4*)(Y8 + (size_t)grow * 256 + br * 128 + quad * 32) =
                *(const uint4*)(hs8 + l16 * 144 + quad * 32);
            *(uint4*)(Y8 + (size_t)grow * 256 + br * 128 + quad * 32 + 16) =
                *(const uint4*)(hs8 + l16 * 144 + quad * 32 + 16);
        }
    } else {
        // pooled accumulation: Sg[br][g][c] += sum over block rows of h
        __syncthreads();                       // w1s reads done by all waves
        float* pl = (float*)lds_all;           // reuse W1 stage region (2 KB)
        for (int i = tid; i < GSPAN * 128; i += 512) pl[i] = 0.f;
        __syncthreads();
        int gmin = batch[blockIdx.x * 128];
        int gidx[4];
#pragma unroll
        for (int r = 0; r < 4; ++r) {
            int node = row0 + quad * 4 + r;
            int gi = -1;
            if (node < n) {
                gi = batch[node] - gmin;
                if (gi < 0) gi = 0;
                if (gi > GSPAN - 1) gi = GSPAN - 1;
            }
            gidx[r] = gi;
        }
#pragma unroll
        for (int nt = 0; nt < 8; ++nt) {
            int c0 = nt * 16 + l16;
#pragma unroll
            for (int r = 0; r < 4; ++r)
                if (gidx[r] >= 0) atomicAdd(&pl[gidx[r] * 128 + c0], acc2_[nt][r]);
        }
        __syncthreads();
        for (int i = tid; i < GSPAN * 128; i += 512) {
            float v = pl[i];
            int g = gmin + (i >> 7);
            if (v != 0.f && g < GG)
                atomicAdd(&Sg[(size_t)br * GG * 128 + g * 128 + (i & 127)], v);
        }
    }
    __syncthreads();
    if (tid < 128) {
        atomicAdd(&statsp[tid], ssum[tid]);
        atomicAdd(&statsp[128 + tid], ssq[tid]);
    }
}

// ---------------- bilinear discriminator (from raw pooled sums) ----------------
__global__ void disc_kernel(const float* __restrict__ Sg, const float* __restrict__ cnt,
                            const float* __restrict__ coefL2,
                            const float* __restrict__ W, const float* __restrict__ db,
                            float* __restrict__ out) {
    int g = blockIdx.x, e = threadIdx.x;
    __shared__ float pg[128], ps[128], rs[128], rh[128];
    float invc = 1.f / fmaxf(cnt[g], 1.f);
    int gs = (g == 32) ? 30 : (63 - g);
    float invcs = 1.f / fmaxf(cnt[gs], 1.f);
    float Ab = coefL2[256 + e], Bb = coefL2[384 + e];
    const float* SB = Sg + (size_t)GG * 128;
    pg[e] = Ab * SB[g * 128 + e] + Bb * cnt[g];
    ps[e] = Ab * SB[gs * 128 + e] + Bb * cnt[gs];
    __syncthreads();
    float t = 0.f;
    for (int d = 0; d < 128; ++d) t += pg[d] * W[d * 128 + e];
    t *= invc;
    rs[e] = t * pg[e] * invc;
    rh[e] = t * ps[e] * invcs;
    __syncthreads();
    for (int s = 64; s > 0; s >>= 1) {
        if (e < s) { rs[e] += rs[e + s]; rh[e] += rh[e + s]; }
        __syncthreads();
    }
    if (e == 0) {
        out[GG * 10 + g] = rs[0] + db[0];
        out[GG * 10 + GG + g] = rh[0] + db[0];
    }
}

// ---------------- classification head (from raw pooled sums) ----------------
__global__ void head_kernel(const float* __restrict__ Sg, const float* __restrict__ cnt,
                            const float* __restrict__ coefL2,
                            const float* __restrict__ w1, const float* __restrict__ b1,
                            const float* __restrict__ w2, const float* __restrict__ b2,
                            float* __restrict__ out) {
    int g = blockIdx.x, j = threadIdx.x;
    __shared__ float ma[128], px[128];
    __shared__ float s1[128];
    __shared__ float s2[10];
    __shared__ float lse;
    float cg = cnt[g];
    float invc = 1.f / fmaxf(cg, 1.f);
    float Aa = coefL2[j],       Ba = coefL2[128 + j];
    float Ab = coefL2[256 + j], Bb = coefL2[384 + j];
    ma[j] = (Aa * Sg[g * 128 + j] + Ba * cg) * invc;
    px[j] = (Ab * Sg[(size_t)GG * 128 + g * 128 + j] + Bb * cg) * invc;
    __syncthreads();
    float acc = b1[j];
    for (int k = 0; k < 128; ++k) acc += ma[k] * w1[k * 128 + j];
    for (int k = 0; k < 128; ++k) acc += px[k] * w1[(128 + k) * 128 + j];
    s1[j] = fmaxf(acc, 0.f);
    __syncthreads();
    if (j < 10) {
        float a = b2[j];
        for (int k = 0; k < 128; ++k) a += s1[k] * w2[k * 10 + j];
        s2[j] = a;
    }
    __syncthreads();
    if (j == 0) {
        float m = s2[0];
        for (int o = 1; o < 10; ++o) m = fmaxf(m, s2[o]);
        float se = 0.f;
        for (int o = 0; o < 10; ++o) se += expf(s2[o] - m);
        lse = m + logf(se);
    }
    __syncthreads();
    if (j < 10) out[g * 10 + j] = s2[j] - lse;
}

extern "C" void kernel_launch(void* const* d_in, const int* in_sizes, int n_in,
                              void* d_out, int out_size, void* d_ws, size_t ws_size,
                              hipStream_t stream) {
    const float* x     = (const float*)d_in[0];
    const int*   ei    = (const int*)d_in[1];
    const int*   batch = (const int*)d_in[2];
    const float* W1a = (const float*)d_in[3];
    const float* b1a = (const float*)d_in[4];
    const float* W2a = (const float*)d_in[5];
    const float* b2a = (const float*)d_in[6];
    const float* ga  = (const float*)d_in[7];
    const float* bta = (const float*)d_in[8];
    const float* W1b = (const float*)d_in[9];
    const float* b1b = (const float*)d_in[10];
    const float* W2b = (const float*)d_in[11];
    const float* b2b = (const float*)d_in[12];
    const float* gb  = (const float*)d_in[13];
    const float* btb = (const float*)d_in[14];
    const float* lin1_w = (const float*)d_in[15];
    const float* lin1_b = (const float*)d_in[16];
    const float* lin2_w = (const float*)d_in[17];
    const float* lin2_b = (const float*)d_in[18];
    const float* disc_w = (const float*)d_in[19];
    const float* disc_b = (const float*)d_in[20];
    float* out = (float*)d_out;

    const int* src = ei;
    const int* dst = ei + EE;

    size_t o = 0;
    auto take = [&](size_t b) { size_t p = o; o = (o + b + 255) & ~(size_t)255; return p; };
    uint8_t* w = (uint8_t*)d_ws;
    size_t o_x8   = take((size_t)NN * 128);
    size_t o_sc0  = take((size_t)NN * 4);
    size_t o_g0   = take((size_t)NN * 128 * 2);
    size_t o_gbuf = take((size_t)NN * 256 * 2);
    size_t o_y8a  = take((size_t)NN * 256);
    size_t o_y8b  = take((size_t)NN * 256);
    size_t o_scA  = take((size_t)NN * 2 * 4);
    size_t o_scB  = take((size_t)NN * 2 * 4);
    size_t o_wf   = take((size_t)12 * MAT_STRIDE * 2);
    size_t o_col  = take((size_t)NBUCK * BCAP * 4);
    size_t o_part = take((size_t)NBUCK * BCAP * 4);
    size_t o_rowpair = take((size_t)NN * 8);
    size_t o_coef = take((size_t)3 * 2 * 256 * 4);
    size_t zero_begin = o;
    size_t o_bcnt   = take((size_t)NBUCK * 4);
    size_t o_stats  = take((size_t)6 * NREP * 256 * 4);
    size_t o_cnt    = take(GG * 4);
    size_t o_Sg     = take((size_t)2 * GG * 128 * 4);
    size_t zero_end = o;

    unsigned short* x8 = (unsigned short*)(w + o_x8);
    float* sc0 = (float*)(w + o_sc0);
    uint32* g0 = (uint32*)(w + o_g0);
    unsigned short* gbuf = (unsigned short*)(w + o_gbuf);
    unsigned char* y8a = (unsigned char*)(w + o_y8a);
    unsigned char* y8b = (unsigned char*)(w + o_y8b);
    float* scA = (float*)(w + o_scA);
    float* scB = (float*)(w + o_scB);
    unsigned short* wf = (unsigned short*)(w + o_wf);
    int* col = (int*)(w + o_col);
    uint32* part = (uint32*)(w + o_part);
    int2* rowpair = (int2*)(w + o_rowpair);
    float* coef = (float*)(w + o_coef);
    int* bcnt = (int*)(w + o_bcnt);
    float* statsRep = (float*)(w + o_stats);
    float* cnt = (float*)(w + o_cnt);
    float* Sg = (float*)(w + o_Sg);

    hipMemsetAsync(w + zero_begin, 0, zero_end - zero_begin, stream);

    x_to_i8_kernel<<<(NN * 64 + 255) / 256, 256, 0, stream>>>(x, x8, sc0);
    convert_w_kernel<<<(24576 + 255) / 256, 256, 0, stream>>>(W1a, W2a, W1b, W2b, wf);

    partition_kernel<<<(EE + PART_CHUNK - 1) / PART_CHUNK, 256, 0, stream>>>(src, dst, bcnt, part);
    build_col_kernel<<<NBUCK, 256, 0, stream>>>(part, bcnt, col, rowpair);
    counts_kernel<<<(NN + 255) / 256, 256, 0, stream>>>(batch, cnt, NN);

    int gatherBlocks = (NN + 3) / 4;
    dim3 mlpGrid((NN + 127) / 128, 2);
    size_t ldsBytes = (size_t)LDS_W1 * 2 + (size_t)LDS_HS * 2 + 256 * 4;  // 68608

    gather0_kernel<<<gatherBlocks, 256, 0, stream>>>(
        (const unsigned char*)x8, sc0, rowpair, col, (uint2*)g0);

    // layer 0: g0 -> y8a
    mlp_dual_kernel<<<mlpGrid, 512, ldsBytes, stream>>>(
        (const unsigned short*)g0, 128, 0, wf, b1a, b1b, b2a, b2b, 0, 1,
        batch, Sg, y8a, scA, statsRep, NN);
    bn_coefs_kernel<<<1, 256, 0, stream>>>(statsRep, ga, bta, gb, btb, 0, coef + 0 * 512);

    // layer 1: gather(y8a) -> gbuf; mlp -> y8b
    gather_dual_kernel<<<gatherBlocks, 256, 0, stream>>>(
        y8a, scA, rowpair, col, coef + 0 * 512, (uint2*)gbuf);
    mlp_dual_kernel<<<mlpGrid, 512, ldsBytes, stream>>>(
        gbuf, 256, 128, wf, b1a, b1b, b2a, b2b, 1, 1,
        batch, Sg, y8b, scB, statsRep, NN);
    bn_coefs_kernel<<<1, 256, 0, stream>>>(statsRep, ga, bta, gb, btb, 1, coef + 1 * 512);

    // layer 2: gather(y8b) -> gbuf; mlp -> pooled sums Sg (no bufP, no pool kernel)
    gather_dual_kernel<<<gatherBlocks, 256, 0, stream>>>(
        y8b, scB, rowpair, col, coef + 1 * 512, (uint2*)gbuf);
    mlp_dual_kernel<<<mlpGrid, 512, ldsBytes, stream>>>(
        gbuf, 256, 128, wf, b1a, b1b, b2a, b2b, 2, 0,
        batch, Sg, nullptr, nullptr, statsRep, NN);
    bn_coefs_kernel<<<1, 256, 0, stream>>>(statsRep, ga, bta, gb, btb, 2, coef + 2 * 512);

    disc_kernel<<<GG, 128, 0, stream>>>(Sg, cnt, coef + 2 * 512, disc_w, disc_b, out);
    head_kernel<<<GG, 128, 0, stream>>>(Sg, cnt, coef + 2 * 512, lin1_w, lin1_b, lin2_w, lin2_b, out);
}

// Round 8
// 607.299 us; speedup vs baseline: 1.2419x; 1.2275x over previous
//
#include <hip/hip_runtime.h>
#include <hip/hip_bf16.h>

#define NN 100000
#define EE 1600000
#define GG 64
#define HH 128
#define LL 3
#define BN_EPS 1e-5f
#define NBUCK 196          // ceil(NN/512)
#define BCAP 12288         // bucket capacity (mean 8163, +45 sigma safe)
#define PART_CHUNK 8192
#define NREP 16            // stats replicas

typedef __attribute__((ext_vector_type(8))) short bf16x8;
typedef __attribute__((ext_vector_type(4))) float f32x4;
typedef unsigned int uint32;

__device__ __forceinline__ unsigned short f2bf(float f) {
    uint32 x = __float_as_uint(f);
    uint32 r = (x + 0x7fffu + ((x >> 16) & 1u)) >> 16;
    return (unsigned short)r;
}
__device__ __forceinline__ float bf2f(unsigned short u) { return __uint_as_float(((uint32)u) << 16); }
// dequant-accumulate 4 unsigned uint8 channels with per-row scale
__device__ __forceinline__ void accq(float4& a, uint32 u, float sc) {
    a.x += sc * (float)(u & 0xffu);
    a.y += sc * (float)((u >> 8) & 0xffu);
    a.z += sc * (float)((u >> 16) & 0xffu);
    a.w += sc * (float)(u >> 24);
}
__device__ __forceinline__ uint32 ld32(const unsigned char* p, uint32 off) {
    return *(const uint32*)(p + off);
}
__device__ __forceinline__ float ldf(const float* p, uint32 byteoff) {
    return *(const float*)((const char*)p + byteoff);
}

// ---------------- bucketed edge partition ----------------
__global__ __launch_bounds__(256) void partition_kernel(
    const int* __restrict__ src, const int* __restrict__ dst,
    int* __restrict__ bcnt, uint32* __restrict__ part) {
    __shared__ int cnt[NBUCK];
    __shared__ int loff[NBUCK + 1];
    __shared__ int gpos[NBUCK];
    __shared__ int lcur[NBUCK];
    __shared__ uint32 buf[PART_CHUNK];
    int tid = threadIdx.x;
    int base = blockIdx.x * PART_CHUNK;
    int n = min(PART_CHUNK, EE - base);
    for (int i = tid; i < NBUCK; i += 256) { cnt[i] = 0; lcur[i] = 0; }
    __syncthreads();
    for (int i = tid; i < n; i += 256) atomicAdd(&cnt[dst[base + i] >> 9], 1);
    __syncthreads();
    if (tid == 0) {
        int acc = 0;
        for (int b = 0; b < NBUCK; ++b) { loff[b] = acc; acc += cnt[b]; }
        loff[NBUCK] = acc;
    }
    __syncthreads();
    if (tid < NBUCK && cnt[tid] > 0) gpos[tid] = atomicAdd(&bcnt[tid], cnt[tid]);
    __syncthreads();
    for (int i = tid; i < n; i += 256) {
        int d = dst[base + i];
        int s = src[base + i];
        int b = d >> 9;
        int slot = atomicAdd(&lcur[b], 1);
        buf[loff[b] + slot] = (uint32)s | ((uint32)(d & 511) << 17);
    }
    __syncthreads();
    for (int i = tid; i < n; i += 256) {
        int lo = 0, hi = NBUCK;
        while (hi - lo > 1) { int mid = (lo + hi) >> 1; if (loff[mid] <= i) lo = mid; else hi = mid; }
        part[(size_t)lo * BCAP + gpos[lo] + (i - loff[lo])] = buf[i];
    }
}

// ---------------- build per-bucket CSR + col (in LDS) ----------------
__global__ __launch_bounds__(256) void build_col_kernel(
    const uint32* __restrict__ part, const int* __restrict__ bcnt,
    int* __restrict__ col, int2* __restrict__ rowpair) {
    __shared__ int ldeg[512];
    __shared__ int loffn[512];
    __shared__ int lcur[512];
    __shared__ int pscan[256];
    __shared__ int cl[BCAP];
    int b = blockIdx.x;
    int tid = threadIdx.x;
    int node0 = b << 9;
    int nn = min(node0 + 512, NN) - node0;
    int cnt = bcnt[b];
    int base = b * BCAP;
    const uint32* pp = part + (size_t)base;
    for (int i = tid; i < 512; i += 256) { ldeg[i] = 0; lcur[i] = 0; }
    __syncthreads();
    for (int i = tid; i < cnt; i += 256) atomicAdd(&ldeg[pp[i] >> 17], 1);
    __syncthreads();
    int t2 = tid * 2;
    int a0 = ldeg[t2], a1 = ldeg[t2 + 1];
    int ps = a0 + a1;
    pscan[tid] = ps;
    __syncthreads();
    for (int off = 1; off < 256; off <<= 1) {
        int v = (tid >= off) ? pscan[tid - off] : 0;
        __syncthreads();
        pscan[tid] += v;
        __syncthreads();
    }
    int eo = pscan[tid] - ps;
    loffn[t2] = eo;
    loffn[t2 + 1] = eo + a0;
    if (t2 < nn)     rowpair[node0 + t2]     = make_int2(base + eo, base + eo + a0);
    if (t2 + 1 < nn) rowpair[node0 + t2 + 1] = make_int2(base + eo + a0, base + eo + a0 + a1);
    __syncthreads();
    for (int i = tid; i < cnt; i += 256) {
        uint32 v = pp[i];
        int dl = (int)(v >> 17);
        int pos = atomicAdd(&lcur[dl], 1);
        cl[loffn[dl] + pos] = (int)(v & 0x1FFFFu);
    }
    __syncthreads();
    for (int i = tid; i < cnt; i += 256) col[base + i] = cl[i];
}

// ---------------- graph counts ----------------
__global__ void counts_kernel(const int* __restrict__ batch, float* __restrict__ cnt, int n) {
    __shared__ int h[GG];
    int tid = threadIdx.x;
    if (tid < GG) h[tid] = 0;
    __syncthreads();
    int i = blockIdx.x * 256 + tid;
    if (i < n) atomicAdd(&h[batch[i]], 1);
    __syncthreads();
    if (tid < GG && h[tid]) atomicAdd(&cnt[tid], (float)h[tid]);
}

// ---------------- x -> biased-uint8 row-quantized ----------------
// stored u = round(v*127/m) + 128; dequant sum: sum s*u - 128*sum s
__global__ void x_to_i8_kernel(const float* __restrict__ x, unsigned short* __restrict__ x8,
                               float* __restrict__ sc0) {
    int row = (blockIdx.x * 256 + threadIdx.x) >> 6;
    int lane = threadIdx.x & 63;
    if (row >= NN) return;
    float2 v = ((const float2*)x)[(size_t)row * 64 + lane];
    float m = fmaxf(fabsf(v.x), fabsf(v.y));
#pragma unroll
    for (int off = 1; off < 64; off <<= 1) m = fmaxf(m, __shfl_xor(m, off));
    float scale = m * (1.f / 127.f);
    float inv = (m > 0.f) ? 127.f / m : 0.f;
    int b0 = __float2int_rn(v.x * inv) + 128;
    int b1 = __float2int_rn(v.y * inv) + 128;
    unsigned short pk = (unsigned short)((b0 & 0xff) | ((b1 & 0xff) << 8));
    x8[(size_t)row * 64 + lane] = pk;
    if (lane == 0) sc0[row] = scale;
}

#define MAT_STRIDE 16384   // ushort elements per frag-ordered matrix

// frag-order weights: [br(2)][l(3)][mat(2)][nt(8)][ks(4)][lane(64)][j(8)]
__global__ void convert_w_kernel(const float* __restrict__ W1a, const float* __restrict__ W2a,
                                 const float* __restrict__ W1b, const float* __restrict__ W2b,
                                 unsigned short* __restrict__ out) {
    int t = blockIdx.x * 256 + threadIdx.x;
    if (t >= 24576) return;
    int lane = t & 63;
    int r = t >> 6;
    int ks = r & 3; r >>= 2;
    int nt = r & 7; r >>= 3;
    int mat = r & 1; r >>= 1;
    int l = r % 3, br = r / 3;
    const float* W = br ? (mat ? W2b : W1b) : (mat ? W2a : W1a);
    const float* Wl = W + (size_t)l * 128 * 128;
    int n0 = nt * 16 + (lane & 15);
    int k0 = ks * 32 + (lane >> 4) * 8;
    unsigned short tmp[8];
#pragma unroll
    for (int j = 0; j < 8; ++j) tmp[j] = f2bf(Wl[(size_t)(k0 + j) * 128 + n0]);
    size_t seq = (size_t)(br * 3 + l) * 2 + mat;
    size_t off = (((seq * 8 + nt) * 4 + ks) * 64 + (size_t)lane) * 8;
    *(uint4*)(out + off) = *(const uint4*)tmp;
}

// ---------------- BN coefs from replicated stats ----------------
__global__ void bn_coefs_kernel(const float* __restrict__ statsRep,
                                const float* __restrict__ ga, const float* __restrict__ bta,
                                const float* __restrict__ gb, const float* __restrict__ btb,
                                int l, float* __restrict__ coef) {
    int t = threadIdx.x;        // 256: br*128+cc
    int br = t >> 7, cc = t & 127;
    const float* base = statsRep + (size_t)((l * 2 + br) * NREP) * 256;
    float s = 0.f, sq = 0.f;
#pragma unroll
    for (int rep = 0; rep < NREP; ++rep) {
        s += base[rep * 256 + cc];
        sq += base[rep * 256 + 128 + cc];
    }
    float mu = s * (1.f / NN);
    float var = sq * (1.f / NN) - mu * mu;
    float gm = (br ? gb : ga)[l * 128 + cc];
    float A = gm * rsqrtf(var + BN_EPS);
    float B = (br ? btb : bta)[l * 128 + cc] - mu * A;
    coef[br * 256 + cc] = A;
    coef[br * 256 + 128 + cc] = B;
}

// ---------------- layer-0 gather on biased-u8 x ----------------
__global__ __launch_bounds__(256) void gather0_kernel(
    const unsigned char* __restrict__ x8b, const float* __restrict__ sc0,
    const int2* __restrict__ rowpair, const int* __restrict__ col,
    uint2* __restrict__ out) {
    int gw = (blockIdx.x * blockDim.x + threadIdx.x) >> 6;
    int lane = threadIdx.x & 63;
    if (gw >= NN) return;
    int slot = lane >> 5;
    int c = lane & 31;
    uint32 c4 = (uint32)c << 2;
    float4 accA = {0.f, 0.f, 0.f, 0.f};
    float4 accB = {0.f, 0.f, 0.f, 0.f};
    float S = 0.f;
    if (slot == 0) {
        float s = sc0[gw];
        uint32 u = ld32(x8b, ((uint32)gw << 7) + c4);
        accq(accA, u, s);
        S += s;
    }
    int2 be = rowpair[gw];
    int beg = be.x, end = be.y;
    for (int base = beg; base < end; base += 64) {
        int nb = min(64, end - base);
        int colv = col[base + min(lane, nb - 1)];
        int k = 0;
        for (; k + 4 <= nb; k += 4) {
            int j0 = __shfl(colv, k + slot);
            int j1 = __shfl(colv, k + 2 + slot);
            float s0 = ldf(sc0, (uint32)j0 << 2);
            float s1 = ldf(sc0, (uint32)j1 << 2);
            uint32 u0 = ld32(x8b, ((uint32)j0 << 7) + c4);
            uint32 u1 = ld32(x8b, ((uint32)j1 << 7) + c4);
            accq(accA, u0, s0); S += s0;
            accq(accB, u1, s1); S += s1;
        }
        for (; k + 2 <= nb; k += 2) {
            int j = __shfl(colv, k + slot);
            float s = ldf(sc0, (uint32)j << 2);
            uint32 u = ld32(x8b, ((uint32)j << 7) + c4);
            accq(accA, u, s); S += s;
        }
        if (k < nb) {
            int j = __shfl(colv, k);
            if (slot == 0) {
                float s = ldf(sc0, (uint32)j << 2);
                uint32 u = ld32(x8b, ((uint32)j << 7) + c4);
                accq(accA, u, s); S += s;
            }
        }
    }
    accA.x += accB.x; accA.y += accB.y; accA.z += accB.z; accA.w += accB.w;
    accA.x += __shfl_xor(accA.x, 32);
    accA.y += __shfl_xor(accA.y, 32);
    accA.z += __shfl_xor(accA.z, 32);
    accA.w += __shfl_xor(accA.w, 32);
    S += __shfl_xor(S, 32);
    float f0 = accA.x - 128.f * S;
    float f1 = accA.y - 128.f * S;
    float f2 = accA.z - 128.f * S;
    float f3 = accA.w - 128.f * S;
    if (slot == 0) {
        uint2 o;
        o.x = (uint32)f2bf(f0) | ((uint32)f2bf(f1) << 16);
        o.y = (uint32)f2bf(f2) | ((uint32)f2bf(f3) << 16);
        out[(uint32)gw * 32 + c] = o;
    }
}

// ---------------- dual-branch gather ----------------
__global__ __launch_bounds__(256) void gather_dual_kernel(
    const unsigned char* __restrict__ y8, const float* __restrict__ scales,
    const int2* __restrict__ rowpair, const int* __restrict__ col,
    const float* __restrict__ coef, uint2* __restrict__ out) {
    int gw = (blockIdx.x * blockDim.x + threadIdx.x) >> 6;
    int lane = threadIdx.x & 63;
    if (gw >= NN) return;
    int br = lane >> 5;
    int c32 = lane & 31;
    uint32 ln4 = (uint32)lane << 2;
    uint32 sb4 = (uint32)br << 2;
    float4 A4 = ((const float4*)(coef + br * 256))[c32];
    float4 B4 = ((const float4*)(coef + br * 256 + 128))[c32];
    float4 accA = {0.f, 0.f, 0.f, 0.f};
    float4 accB = {0.f, 0.f, 0.f, 0.f};
    {
        float s = ldf(scales, ((uint32)gw << 3) + sb4);
        uint32 u = ld32(y8, ((uint32)gw << 8) + ln4);
        accq(accA, u, s);
    }
    int2 be = rowpair[gw];
    int beg = be.x, end = be.y;
    float degp1 = (float)(end - beg + 1);
    for (int base = beg; base < end; base += 64) {
        int nb = min(64, end - base);
        int colv = col[base + min(lane, nb - 1)];
        int k = 0;
        for (; k + 4 <= nb; k += 4) {
            int j0 = __builtin_amdgcn_readlane(colv, k);
            int j1 = __builtin_amdgcn_readlane(colv, k + 1);
            int j2 = __builtin_amdgcn_readlane(colv, k + 2);
            int j3 = __builtin_amdgcn_readlane(colv, k + 3);
            float s0 = ldf(scales, ((uint32)j0 << 3) + sb4);
            float s1 = ldf(scales, ((uint32)j1 << 3) + sb4);
            float s2 = ldf(scales, ((uint32)j2 << 3) + sb4);
            float s3 = ldf(scales, ((uint32)j3 << 3) + sb4);
            uint32 u0 = ld32(y8, ((uint32)j0 << 8) + ln4);
            uint32 u1 = ld32(y8, ((uint32)j1 << 8) + ln4);
            uint32 u2 = ld32(y8, ((uint32)j2 << 8) + ln4);
            uint32 u3 = ld32(y8, ((uint32)j3 << 8) + ln4);
            accq(accA, u0, s0);
            accq(accB, u1, s1);
            accq(accA, u2, s2);
            accq(accB, u3, s3);
        }
        for (; k < nb; ++k) {
            int j = __builtin_amdgcn_readlane(colv, k);
            float s = ldf(scales, ((uint32)j << 3) + sb4);
            uint32 u = ld32(y8, ((uint32)j << 8) + ln4);
            accq(accA, u, s);
        }
    }
    float o0 = A4.x * (accA.x + accB.x) + B4.x * degp1;
    float o1 = A4.y * (accA.y + accB.y) + B4.y * degp1;
    float o2 = A4.z * (accA.z + accB.z) + B4.z * degp1;
    float o3 = A4.w * (accA.w + accB.w) + B4.w * degp1;
    uint2 o;
    o.x = (uint32)f2bf(o0) | ((uint32)f2bf(o1) << 16);
    o.y = (uint32)f2bf(o2) | ((uint32)f2bf(o3) << 16);
    out[(size_t)gw * 64 + lane] = o;
}

// ---------------- fused dual-branch MLP (round-5 body): 512 threads, W1 LDS stage --------
// quant=0 (layer 2): wave-level pooled accumulation into Sg via shfl-reduce +
// direct global atomics (batch sorted -> one graph per wave except boundaries).
#define LDS_W1 16384
#define LDS_HS (8 * 16 * 136)
__global__ __launch_bounds__(512, 4) void mlp_dual_kernel(
    const unsigned short* __restrict__ X, int in_stride, int in_off_mul,
    const unsigned short* __restrict__ wf_all,
    const float* __restrict__ b1a, const float* __restrict__ b1b,
    const float* __restrict__ b2a, const float* __restrict__ b2b,
    int l, int quant,
    const int* __restrict__ batch, float* __restrict__ Sg,
    unsigned char* __restrict__ Y8,
    float* __restrict__ scales, float* __restrict__ statsRep, int n) {
    extern __shared__ unsigned short lds_all[];
    unsigned short* w1s = lds_all;
    unsigned short (*hs)[16][136] = (unsigned short (*)[16][136])(lds_all + LDS_W1);
    float* ssum = (float*)(lds_all + LDS_W1 + LDS_HS);
    float* ssq = ssum + 128;

    int br = blockIdx.y;
    const unsigned short* Wf = wf_all + (size_t)(br * 3 + l) * 2 * MAT_STRIDE;
    const float* b1 = (br ? b1b : b1a) + l * 128;
    const float* b2 = (br ? b2b : b2a) + l * 128;
    float* statsp = statsRep + (size_t)((l * 2 + br) * NREP + (blockIdx.x & (NREP - 1))) * 256;
    int in_off = in_off_mul * br;

    int tid = threadIdx.x;
    int wv = tid >> 6, lane = tid & 63;
    int quad = lane >> 4, l16 = lane & 15;

    const bf16x8* w2g = (const bf16x8*)(Wf + MAT_STRIDE);

    bf16x8 w2p[2][4];
#pragma unroll
    for (int p = 0; p < 2; ++p)
#pragma unroll
        for (int ks = 0; ks < 4; ++ks) w2p[p][ks] = w2g[(p * 4 + ks) * 64 + lane];

    int row0 = blockIdx.x * 128 + wv * 16;

    bf16x8 aF[4];
    {
        int r = row0 + l16;
        if (r >= n) r = n - 1;
        const unsigned short* xrow = X + (size_t)r * in_stride + in_off;
#pragma unroll
        for (int ks = 0; ks < 4; ++ks) aF[ks] = *(const bf16x8*)(xrow + ks * 32 + quad * 8);
    }

    {
        const uint4* srcp = (const uint4*)Wf;
        uint4* dstp = (uint4*)w1s;
        for (int i = tid; i < 2048; i += 512) dstp[i] = srcp[i];
    }
    if (tid < 128) { ssum[tid] = 0.f; ssq[tid] = 0.f; }
    __syncthreads();

    f32x4 acc1[8];
#pragma unroll
    for (int nt = 0; nt < 8; ++nt) {
        f32x4 c = {0.f, 0.f, 0.f, 0.f};
#pragma unroll
        for (int ks = 0; ks < 4; ++ks) {
            bf16x8 bfrag = *(const bf16x8*)(&w1s[((nt * 4 + ks) * 64 + lane) * 8]);
            c = __builtin_amdgcn_mfma_f32_16x16x32_bf16(aF[ks], bfrag, c, 0, 0, 0);
        }
        acc1[nt] = c;
    }

#pragma unroll
    for (int nt = 0; nt < 8; ++nt) {
        int c0 = nt * 16 + l16;
        float bb = b1[c0];
#pragma unroll
        for (int r = 0; r < 4; ++r) {
            float v = fmaxf(acc1[nt][r] + bb, 0.f);
            hs[wv][quad * 4 + r][c0] = f2bf(v);
        }
    }

    bf16x8 aH[4];
#pragma unroll
    for (int ks = 0; ks < 4; ++ks)
        aH[ks] = *(const bf16x8*)(&hs[wv][l16][ks * 32 + quad * 8]);

    f32x4 acc2_[8];
#pragma unroll
    for (int nt = 0; nt < 8; ++nt) {
        bf16x8 bf0, bf1, bf2, bf3;
        if (nt < 2) { bf0 = w2p[nt][0]; bf1 = w2p[nt][1]; bf2 = w2p[nt][2]; bf3 = w2p[nt][3]; }
        else {
            bf0 = w2g[(nt * 4 + 0) * 64 + lane];
            bf1 = w2g[(nt * 4 + 1) * 64 + lane];
            bf2 = w2g[(nt * 4 + 2) * 64 + lane];
            bf3 = w2g[(nt * 4 + 3) * 64 + lane];
        }
        f32x4 c = {0.f, 0.f, 0.f, 0.f};
        c = __builtin_amdgcn_mfma_f32_16x16x32_bf16(aH[0], bf0, c, 0, 0, 0);
        c = __builtin_amdgcn_mfma_f32_16x16x32_bf16(aH[1], bf1, c, 0, 0, 0);
        c = __builtin_amdgcn_mfma_f32_16x16x32_bf16(aH[2], bf2, c, 0, 0, 0);
        c = __builtin_amdgcn_mfma_f32_16x16x32_bf16(aH[3], bf3, c, 0, 0, 0);
        acc2_[nt] = c;
    }

#pragma unroll
    for (int nt = 0; nt < 8; ++nt) {
        int c0 = nt * 16 + l16;
        float bb = b2[c0];
        float s = 0.f, sq = 0.f;
#pragma unroll
        for (int r = 0; r < 4; ++r) {
            float v = fmaxf(acc2_[nt][r] + bb, 0.f);
            if (row0 + quad * 4 + r >= n) v = 0.f;
            acc2_[nt][r] = v;
            s += v; sq += v * v;
        }
        s += __shfl_xor(s, 16); s += __shfl_xor(s, 32);
        sq += __shfl_xor(sq, 16); sq += __shfl_xor(sq, 32);
        if (quad == 0) { atomicAdd(&ssum[c0], s); atomicAdd(&ssq[c0], sq); }
    }

    if (quant) {
        unsigned char* hs8 = (unsigned char*)&hs[wv][0][0];
#pragma unroll
        for (int r = 0; r < 4; ++r) {
            float m = acc2_[0][r];
#pragma unroll
            for (int nt = 1; nt < 8; ++nt) m = fmaxf(m, acc2_[nt][r]);
            m = fmaxf(m, __shfl_xor(m, 1));
            m = fmaxf(m, __shfl_xor(m, 2));
            m = fmaxf(m, __shfl_xor(m, 4));
            m = fmaxf(m, __shfl_xor(m, 8));
            float sc = m * (1.f / 255.f);
            float inv = (m > 0.f) ? 255.f / m : 0.f;
            int grow = row0 + quad * 4 + r;
            if (l16 == r && grow < n) scales[grow * 2 + br] = sc;
#pragma unroll
            for (int nt = 0; nt < 8; ++nt) {
                uint32 u = (uint32)__float2int_rn(acc2_[nt][r] * inv);
                hs8[(quad * 4 + r) * 144 + nt * 16 + l16] = (unsigned char)u;
            }
        }
        int grow = row0 + l16;
        if (grow < n) {
            *(uint4*)(Y8 + (size_t)grow * 256 + br * 128 + quad * 32) =
                *(const uint4*)(hs8 + l16 * 144 + quad * 32);
            *(uint4*)(Y8 + (size_t)grow * 256 + br * 128 + quad * 32 + 16) =
                *(const uint4*)(hs8 + l16 * 144 + quad * 32 + 16);
        }
    } else {
        // wave-level pooled accumulation into Sg[br][g][c].
        // batch is sorted: whole wave (16 rows) is one graph unless a boundary
        // falls inside (rare). Rows >= n were zeroed above (safe to add).
        float* sgb = Sg + (size_t)br * GG * 128;
        int gFirst = batch[min(row0, n - 1)];
        int gLast = batch[min(row0 + 15, n - 1)];
        if (gFirst == gLast) {
#pragma unroll
            for (int nt = 0; nt < 8; ++nt) {
                float s = (acc2_[nt][0] + acc2_[nt][1]) + (acc2_[nt][2] + acc2_[nt][3]);
                s += __shfl_xor(s, 16);
                s += __shfl_xor(s, 32);
                if (quad == 0) atomicAdd(&sgb[gFirst * 128 + nt * 16 + l16], s);
            }
        } else {
#pragma unroll
            for (int r = 0; r < 4; ++r) {
                int node = row0 + quad * 4 + r;
                if (node < n) {
                    int g = batch[node];
#pragma unroll
                    for (int nt = 0; nt < 8; ++nt)
                        atomicAdd(&sgb[g * 128 + nt * 16 + l16], acc2_[nt][r]);
                }
            }
        }
    }
    __syncthreads();
    if (tid < 128) {
        atomicAdd(&statsp[tid], ssum[tid]);
        atomicAdd(&statsp[128 + tid], ssq[tid]);
    }
}

// ---------------- bilinear discriminator (from raw pooled sums) ----------------
__global__ void disc_kernel(const float* __restrict__ Sg, const float* __restrict__ cnt,
                            const float* __restrict__ coefL2,
                            const float* __restrict__ W, const float* __restrict__ db,
                            float* __restrict__ out) {
    int g = blockIdx.x, e = threadIdx.x;
    __shared__ float pg[128], ps[128], rs[128], rh[128];
    float invc = 1.f / fmaxf(cnt[g], 1.f);
    int gs = (g == 32) ? 30 : (63 - g);
    float invcs = 1.f / fmaxf(cnt[gs], 1.f);
    float Ab = coefL2[256 + e], Bb = coefL2[384 + e];
    const float* SB = Sg + (size_t)GG * 128;
    pg[e] = Ab * SB[g * 128 + e] + Bb * cnt[g];
    ps[e] = Ab * SB[gs * 128 + e] + Bb * cnt[gs];
    __syncthreads();
    float t = 0.f;
    for (int d = 0; d < 128; ++d) t += pg[d] * W[d * 128 + e];
    t *= invc;
    rs[e] = t * pg[e] * invc;
    rh[e] = t * ps[e] * invcs;
    __syncthreads();
    for (int s = 64; s > 0; s >>= 1) {
        if (e < s) { rs[e] += rs[e + s]; rh[e] += rh[e + s]; }
        __syncthreads();
    }
    if (e == 0) {
        out[GG * 10 + g] = rs[0] + db[0];
        out[GG * 10 + GG + g] = rh[0] + db[0];
    }
}

// ---------------- classification head (from raw pooled sums) ----------------
__global__ void head_kernel(const float* __restrict__ Sg, const float* __restrict__ cnt,
                            const float* __restrict__ coefL2,
                            const float* __restrict__ w1, const float* __restrict__ b1,
                            const float* __restrict__ w2, const float* __restrict__ b2,
                            float* __restrict__ out) {
    int g = blockIdx.x, j = threadIdx.x;
    __shared__ float ma[128], px[128];
    __shared__ float s1[128];
    __shared__ float s2[10];
    __shared__ float lse;
    float cg = cnt[g];
    float invc = 1.f / fmaxf(cg, 1.f);
    float Aa = coefL2[j],       Ba = coefL2[128 + j];
    float Ab = coefL2[256 + j], Bb = coefL2[384 + j];
    ma[j] = (Aa * Sg[g * 128 + j] + Ba * cg) * invc;
    px[j] = (Ab * Sg[(size_t)GG * 128 + g * 128 + j] + Bb * cg) * invc;
    __syncthreads();
    float acc = b1[j];
    for (int k = 0; k < 128; ++k) acc += ma[k] * w1[k * 128 + j];
    for (int k = 0; k < 128; ++k) acc += px[k] * w1[(128 + k) * 128 + j];
    s1[j] = fmaxf(acc, 0.f);
    __syncthreads();
    if (j < 10) {
        float a = b2[j];
        for (int k = 0; k < 128; ++k) a += s1[k] * w2[k * 10 + j];
        s2[j] = a;
    }
    __syncthreads();
    if (j == 0) {
        float m = s2[0];
        for (int o = 1; o < 10; ++o) m = fmaxf(m, s2[o]);
        float se = 0.f;
        for (int o = 0; o < 10; ++o) se += expf(s2[o] - m);
        lse = m + logf(se);
    }
    __syncthreads();
    if (j < 10) out[g * 10 + j] = s2[j] - lse;
}

extern "C" void kernel_launch(void* const* d_in, const int* in_sizes, int n_in,
                              void* d_out, int out_size, void* d_ws, size_t ws_size,
                              hipStream_t stream) {
    const float* x     = (const float*)d_in[0];
    const int*   ei    = (const int*)d_in[1];
    const int*   batch = (const int*)d_in[2];
    const float* W1a = (const float*)d_in[3];
    const float* b1a = (const float*)d_in[4];
    const float* W2a = (const float*)d_in[5];
    const float* b2a = (const float*)d_in[6];
    const float* ga  = (const float*)d_in[7];
    const float* bta = (const float*)d_in[8];
    const float* W1b = (const float*)d_in[9];
    const float* b1b = (const float*)d_in[10];
    const float* W2b = (const float*)d_in[11];
    const float* b2b = (const float*)d_in[12];
    const float* gb  = (const float*)d_in[13];
    const float* btb = (const float*)d_in[14];
    const float* lin1_w = (const float*)d_in[15];
    const float* lin1_b = (const float*)d_in[16];
    const float* lin2_w = (const float*)d_in[17];
    const float* lin2_b = (const float*)d_in[18];
    const float* disc_w = (const float*)d_in[19];
    const float* disc_b = (const float*)d_in[20];
    float* out = (float*)d_out;

    const int* src = ei;
    const int* dst = ei + EE;

    size_t o = 0;
    auto take = [&](size_t b) { size_t p = o; o = (o + b + 255) & ~(size_t)255; return p; };
    uint8_t* w = (uint8_t*)d_ws;
    size_t o_x8   = take((size_t)NN * 128);
    size_t o_sc0  = take((size_t)NN * 4);
    size_t o_g0   = take((size_t)NN * 128 * 2);
    size_t o_gbuf = take((size_t)NN * 256 * 2);
    size_t o_y8a  = take((size_t)NN * 256);
    size_t o_y8b  = take((size_t)NN * 256);
    size_t o_scA  = take((size_t)NN * 2 * 4);
    size_t o_scB  = take((size_t)NN * 2 * 4);
    size_t o_wf   = take((size_t)12 * MAT_STRIDE * 2);
    size_t o_col  = take((size_t)NBUCK * BCAP * 4);
    size_t o_part = take((size_t)NBUCK * BCAP * 4);
    size_t o_rowpair = take((size_t)NN * 8);
    size_t o_coef = take((size_t)3 * 2 * 256 * 4);
    size_t zero_begin = o;
    size_t o_bcnt   = take((size_t)NBUCK * 4);
    size_t o_stats  = take((size_t)6 * NREP * 256 * 4);
    size_t o_cnt    = take(GG * 4);
    size_t o_Sg     = take((size_t)2 * GG * 128 * 4);
    size_t zero_end = o;

    unsigned short* x8 = (unsigned short*)(w + o_x8);
    float* sc0 = (float*)(w + o_sc0);
    uint32* g0 = (uint32*)(w + o_g0);
    unsigned short* gbuf = (unsigned short*)(w + o_gbuf);
    unsigned char* y8a = (unsigned char*)(w + o_y8a);
    unsigned char* y8b = (unsigned char*)(w + o_y8b);
    float* scA = (float*)(w + o_scA);
    float* scB = (float*)(w + o_scB);
    unsigned short* wf = (unsigned short*)(w + o_wf);
    int* col = (int*)(w + o_col);
    uint32* part = (uint32*)(w + o_part);
    int2* rowpair = (int2*)(w + o_rowpair);
    float* coef = (float*)(w + o_coef);
    int* bcnt = (int*)(w + o_bcnt);
    float* statsRep = (float*)(w + o_stats);
    float* cnt = (float*)(w + o_cnt);
    float* Sg = (float*)(w + o_Sg);

    hipMemsetAsync(w + zero_begin, 0, zero_end - zero_begin, stream);

    x_to_i8_kernel<<<(NN * 64 + 255) / 256, 256, 0, stream>>>(x, x8, sc0);
    convert_w_kernel<<<(24576 + 255) / 256, 256, 0, stream>>>(W1a, W2a, W1b, W2b, wf);

    partition_kernel<<<(EE + PART_CHUNK - 1) / PART_CHUNK, 256, 0, stream>>>(src, dst, bcnt, part);
    build_col_kernel<<<NBUCK, 256, 0, stream>>>(part, bcnt, col, rowpair);
    counts_kernel<<<(NN + 255) / 256, 256, 0, stream>>>(batch, cnt, NN);

    int gatherBlocks = (NN + 3) / 4;
    dim3 mlpGrid((NN + 127) / 128, 2);
    size_t ldsBytes = (size_t)LDS_W1 * 2 + (size_t)LDS_HS * 2 + 256 * 4;  // 68608

    gather0_kernel<<<gatherBlocks, 256, 0, stream>>>(
        (const unsigned char*)x8, sc0, rowpair, col, (uint2*)g0);

    // layer 0: g0 -> y8a
    mlp_dual_kernel<<<mlpGrid, 512, ldsBytes, stream>>>(
        (const unsigned short*)g0, 128, 0, wf, b1a, b1b, b2a, b2b, 0, 1,
        batch, Sg, y8a, scA, statsRep, NN);
    bn_coefs_kernel<<<1, 256, 0, stream>>>(statsRep, ga, bta, gb, btb, 0, coef + 0 * 512);

    // layer 1: gather(y8a) -> gbuf; mlp -> y8b
    gather_dual_kernel<<<gatherBlocks, 256, 0, stream>>>(
        y8a, scA, rowpair, col, coef + 0 * 512, (uint2*)gbuf);
    mlp_dual_kernel<<<mlpGrid, 512, ldsBytes, stream>>>(
        gbuf, 256, 128, wf, b1a, b1b, b2a, b2b, 1, 1,
        batch, Sg, y8b, scB, statsRep, NN);
    bn_coefs_kernel<<<1, 256, 0, stream>>>(statsRep, ga, bta, gb, btb, 1, coef + 1 * 512);

    // layer 2: gather(y8b) -> gbuf; mlp -> pooled sums Sg (no bufP, no pool kernel)
    gather_dual_kernel<<<gatherBlocks, 256, 0, stream>>>(
        y8b, scB, rowpair, col, coef + 1 * 512, (uint2*)gbuf);
    mlp_dual_kernel<<<mlpGrid, 512, ldsBytes, stream>>>(
        gbuf, 256, 128, wf, b1a, b1b, b2a, b2b, 2, 0,
        batch, Sg, nullptr, nullptr, statsRep, NN);
    bn_coefs_kernel<<<1, 256, 0, stream>>>(statsRep, ga, bta, gb, btb, 2, coef + 2 * 512);

    disc_kernel<<<GG, 128, 0, stream>>>(Sg, cnt, coef + 2 * 512, disc_w, disc_b, out);
    head_kernel<<<GG, 128, 0, stream>>>(Sg, cnt, coef + 2 * 512, lin1_w, lin1_b, lin2_w, lin2_b, out);
}